// Round 1
// baseline (849.165 us; speedup 1.0000x reference)
//
#include <hip/hip_runtime.h>

#define NF 128
#define NC 64

static inline size_t alignup(size_t x){ return (x + 255) & ~(size_t)255; }

// ---------- CSR build ----------
__global__ void k_count(const int* __restrict__ dst, int* __restrict__ deg, int E){
  int i = blockIdx.x*256 + threadIdx.x;
  if (i < E) atomicAdd(&deg[dst[i]], 1);
}

__global__ void k_scanA(const int* __restrict__ deg, int* __restrict__ off, int* __restrict__ bsum, int n){
  __shared__ int sh[256];
  int t = threadIdx.x;
  int i = blockIdx.x*256 + t;
  int v = (i < n) ? deg[i] : 0;
  sh[t] = v; __syncthreads();
  for (int o = 1; o < 256; o <<= 1){
    int u = (t >= o) ? sh[t-o] : 0;
    __syncthreads();
    sh[t] += u;
    __syncthreads();
  }
  if (i < n) off[i] = sh[t];           // inclusive within block
  if (t == 255) bsum[blockIdx.x] = sh[255];
}

__global__ void k_scanB(const int* __restrict__ bsum, int* __restrict__ boff, int nb, int* __restrict__ off, int n){
  __shared__ int sh[512];
  int t = threadIdx.x;
  int v = (t < nb) ? bsum[t] : 0;
  sh[t] = v; __syncthreads();
  for (int o = 1; o < 512; o <<= 1){
    int u = (t >= o) ? sh[t-o] : 0;
    __syncthreads();
    sh[t] += u;
    __syncthreads();
  }
  if (t < nb) boff[t] = sh[t] - v;     // exclusive block offsets
  if (t == nb-1) off[n] = sh[t];       // total edge count at off[N]
}

__global__ void k_scanC(const int* __restrict__ deg, int* __restrict__ off, const int* __restrict__ boff, int n){
  int i = blockIdx.x*256 + threadIdx.x;
  if (i < n) off[i] = off[i] - deg[i] + boff[blockIdx.x];  // global exclusive
}

__global__ void k_fill(const int* __restrict__ src, const int* __restrict__ dst, const float* __restrict__ w,
                       const int* __restrict__ off, int* __restrict__ cnt, int2* __restrict__ csr, int E){
  int i = blockIdx.x*256 + threadIdx.x;
  if (i >= E) return;
  int d = dst[i];
  int p = off[d] + atomicAdd(&cnt[d], 1);
  csr[p] = make_int2(src[i], __float_as_int(w[i]));
}

// ---------- SpMM: one wave per destination node, pure gather ----------
__global__ __launch_bounds__(256) void k_spmm(const float* __restrict__ x, const int2* __restrict__ csr,
    const int* __restrict__ off, float* __restrict__ out, int n){
  int wid  = (blockIdx.x * 256 + threadIdx.x) >> 6;
  int lane = threadIdx.x & 63;
  if (wid >= n) return;
  int s = off[wid], e = off[wid+1];
  float ax = 0.f, ay = 0.f;
  for (int j = s; j < e; ++j) {
    int2 ed = csr[j];                                   // wave-uniform address -> broadcast
    float w = __int_as_float(ed.y);
    float2 xv = ((const float2*)(x + (size_t)ed.x * NF))[lane];  // 512B coalesced row read
    ax = fmaf(w, xv.x, ax);
    ay = fmaf(w, xv.y, ay);
  }
  ((float2*)(out + (size_t)wid * NF))[lane] = make_float2(ax, ay);
}

// ---------- GEMM1 (128x128) + bias + ReLU, W in LDS, 2 rows per wave ----------
__global__ __launch_bounds__(256) void k_gemm_relu(const float* __restrict__ hin, const float* __restrict__ W,
    const float* __restrict__ bias, float* __restrict__ hout, int n){
  __shared__ float wl[NF*NF];
  for (int i = threadIdx.x; i < NF*NF/4; i += 256) ((float4*)wl)[i] = ((const float4*)W)[i];
  __syncthreads();
  int lane = threadIdx.x & 63;
  int gw = (blockIdx.x * 256 + threadIdx.x) >> 6;
  int nw = gridDim.x * 4;
  float2 bv = ((const float2*)bias)[lane];
  for (int r0 = gw*2; r0 < n; r0 += nw*2) {
    bool has1 = (r0 + 1) < n;
    const float* row0 = hin + (size_t)r0 * NF;
    const float* row1 = hin + (size_t)(has1 ? r0+1 : r0) * NF;
    float a0lo = row0[lane], a0hi = row0[lane+64];
    float a1lo = row1[lane], a1hi = row1[lane+64];
    float acc0x=0.f, acc0y=0.f, acc1x=0.f, acc1y=0.f;
    #pragma unroll 8
    for (int k = 0; k < 64; ++k){
      float a0 = __shfl(a0lo, k);
      float a1 = __shfl(a1lo, k);
      float2 wv = ((const float2*)(wl + k*NF))[lane];
      acc0x = fmaf(a0, wv.x, acc0x); acc0y = fmaf(a0, wv.y, acc0y);
      acc1x = fmaf(a1, wv.x, acc1x); acc1y = fmaf(a1, wv.y, acc1y);
    }
    #pragma unroll 8
    for (int k = 0; k < 64; ++k){
      float a0 = __shfl(a0hi, k);
      float a1 = __shfl(a1hi, k);
      float2 wv = ((const float2*)(wl + (k+64)*NF))[lane];
      acc0x = fmaf(a0, wv.x, acc0x); acc0y = fmaf(a0, wv.y, acc0y);
      acc1x = fmaf(a1, wv.x, acc1x); acc1y = fmaf(a1, wv.y, acc1y);
    }
    float2 o0 = make_float2(fmaxf(acc0x + bv.x, 0.f), fmaxf(acc0y + bv.y, 0.f));
    ((float2*)(hout + (size_t)r0*NF))[lane] = o0;
    if (has1) {
      float2 o1 = make_float2(fmaxf(acc1x + bv.x, 0.f), fmaxf(acc1y + bv.y, 0.f));
      ((float2*)(hout + (size_t)(r0+1)*NF))[lane] = o1;
    }
  }
}

// ---------- GEMM2 (128x64) + bias + log_softmax, lane == class ----------
__global__ __launch_bounds__(256) void k_gemm_ls(const float* __restrict__ hin, const float* __restrict__ W,
    const float* __restrict__ bias, float* __restrict__ out, int n){
  __shared__ float wl[NF*NC];
  for (int i = threadIdx.x; i < NF*NC/4; i += 256) ((float4*)wl)[i] = ((const float4*)W)[i];
  __syncthreads();
  int lane = threadIdx.x & 63;
  int gw = (blockIdx.x * 256 + threadIdx.x) >> 6;
  int nw = gridDim.x * 4;
  float bv = bias[lane];
  for (int r0 = gw*2; r0 < n; r0 += nw*2) {
    bool has1 = (r0 + 1) < n;
    const float* row0 = hin + (size_t)r0 * NF;
    const float* row1 = hin + (size_t)(has1 ? r0+1 : r0) * NF;
    float a0lo = row0[lane], a0hi = row0[lane+64];
    float a1lo = row1[lane], a1hi = row1[lane+64];
    float z0 = bv, z1 = bv;
    #pragma unroll 8
    for (int k = 0; k < 64; ++k){
      float wv = wl[k*NC + lane];
      z0 = fmaf(__shfl(a0lo, k), wv, z0);
      z1 = fmaf(__shfl(a1lo, k), wv, z1);
    }
    #pragma unroll 8
    for (int k = 0; k < 64; ++k){
      float wv = wl[(k+64)*NC + lane];
      z0 = fmaf(__shfl(a0hi, k), wv, z0);
      z1 = fmaf(__shfl(a1hi, k), wv, z1);
    }
    // log_softmax across the 64 lanes (= 64 classes)
    float m0 = z0, m1 = z1;
    for (int o = 32; o; o >>= 1){ m0 = fmaxf(m0, __shfl_xor(m0, o)); m1 = fmaxf(m1, __shfl_xor(m1, o)); }
    float e0 = expf(z0 - m0), e1 = expf(z1 - m1);
    float s0 = e0, s1 = e1;
    for (int o = 32; o; o >>= 1){ s0 += __shfl_xor(s0, o); s1 += __shfl_xor(s1, o); }
    out[(size_t)r0*NC + lane] = z0 - m0 - logf(s0);
    if (has1) out[(size_t)(r0+1)*NC + lane] = z1 - m1 - logf(s1);
  }
}

extern "C" void kernel_launch(void* const* d_in, const int* in_sizes, int n_in,
                              void* d_out, int out_size, void* d_ws, size_t ws_size,
                              hipStream_t stream){
  const float* x  = (const float*)d_in[0];
  const int* esrc = (const int*)d_in[1];
  const int* edst = (const int*)d_in[2];
  const float* ew = (const float*)d_in[3];
  const float* W0 = (const float*)d_in[4];
  const float* b0 = (const float*)d_in[5];
  const float* W1 = (const float*)d_in[6];
  const float* b1 = (const float*)d_in[7];
  float* out = (float*)d_out;

  const int N = in_sizes[0] / NF;
  const int E = in_sizes[1];

  char* ws = (char*)d_ws;
  size_t o = 0;
  int*  deg  = (int*) (ws + o); o = alignup(o + (size_t)N*4);
  int*  off  = (int*) (ws + o); o = alignup(o + (size_t)(N+1)*4);
  int*  cnt  = (int*) (ws + o); o = alignup(o + (size_t)N*4);
  int*  bsum = (int*) (ws + o); o = alignup(o + 4096);
  int*  boff = (int*) (ws + o); o = alignup(o + 4096);
  int2* csr  = (int2*)(ws + o); o = alignup(o + (size_t)E*8);
  float* h1  = (float*)(ws + o); o = alignup(o + (size_t)N*NF*4);
  float* h   = (float*)(ws + o); o = alignup(o + (size_t)N*NF*4);
  // h2 (second aggregation output) reuses h1's buffer

  hipMemsetAsync(deg, 0, (size_t)N*4, stream);
  hipMemsetAsync(cnt, 0, (size_t)N*4, stream);

  const int eb = (E + 255)/256;
  const int nb = (N + 255)/256;   // 391 <= 512, fits single-block scanB

  k_count<<<eb, 256, 0, stream>>>(edst, deg, E);
  k_scanA<<<nb, 256, 0, stream>>>(deg, off, bsum, N);
  k_scanB<<<1, 512, 0, stream>>>(bsum, boff, nb, off, N);
  k_scanC<<<nb, 256, 0, stream>>>(deg, off, boff, N);
  k_fill<<<eb, 256, 0, stream>>>(esrc, edst, ew, off, cnt, csr, E);

  const int sb = (N + 3)/4;       // 4 waves per block, 1 node per wave
  k_spmm<<<sb, 256, 0, stream>>>(x, csr, off, h1, N);
  k_gemm_relu<<<2048, 256, 0, stream>>>(h1, W0, b0, h, N);
  k_spmm<<<sb, 256, 0, stream>>>(h, csr, off, h1, N);
  k_gemm_ls<<<2048, 256, 0, stream>>>(h1, W1, b1, out, N);
}

// Round 2
// 624.904 us; speedup vs baseline: 1.3589x; 1.3589x over previous
//
#include <hip/hip_runtime.h>

#define NF 128
#define NC 64

static inline size_t alignup(size_t x){ return (x + 255) & ~(size_t)255; }

// ---------- CSR build ----------
__global__ void k_count(const int* __restrict__ dst, int* __restrict__ deg, int E){
  int i = blockIdx.x*256 + threadIdx.x;
  if (i < E) atomicAdd(&deg[dst[i]], 1);
}

__global__ void k_scanA(const int* __restrict__ deg, int* __restrict__ off, int* __restrict__ bsum, int n){
  __shared__ int sh[256];
  int t = threadIdx.x;
  int i = blockIdx.x*256 + t;
  int v = (i < n) ? deg[i] : 0;
  sh[t] = v; __syncthreads();
  for (int o = 1; o < 256; o <<= 1){
    int u = (t >= o) ? sh[t-o] : 0;
    __syncthreads();
    sh[t] += u;
    __syncthreads();
  }
  if (i < n) off[i] = sh[t];
  if (t == 255) bsum[blockIdx.x] = sh[255];
}

__global__ void k_scanB(const int* __restrict__ bsum, int* __restrict__ boff, int nb, int* __restrict__ off, int n){
  __shared__ int sh[512];
  int t = threadIdx.x;
  int v = (t < nb) ? bsum[t] : 0;
  sh[t] = v; __syncthreads();
  for (int o = 1; o < 512; o <<= 1){
    int u = (t >= o) ? sh[t-o] : 0;
    __syncthreads();
    sh[t] += u;
    __syncthreads();
  }
  if (t < nb) boff[t] = sh[t] - v;
  if (t == nb-1) off[n] = sh[t];
}

__global__ void k_scanC(const int* __restrict__ deg, int* __restrict__ off, const int* __restrict__ boff, int n){
  int i = blockIdx.x*256 + threadIdx.x;
  if (i < n) off[i] = off[i] - deg[i] + boff[blockIdx.x];
}

__global__ void k_fill(const int* __restrict__ src, const int* __restrict__ dst, const float* __restrict__ w,
                       const int* __restrict__ off, int* __restrict__ cnt, int2* __restrict__ csr, int E){
  int i = blockIdx.x*256 + threadIdx.x;
  if (i >= E) return;
  int d = dst[i];
  int p = off[d] + atomicAdd(&cnt[d], 1);
  csr[p] = make_int2(src[i], __float_as_int(w[i]));
}

// ---------- GEMM1: Y = A @ W  (n x 128 @ 128 x 128), register-tiled ----------
// 256 thr, 128-row tile, micro 8x8. A in LDS (pad 129 -> conflict-free a-reads),
// W streamed from L1/L2 (shared by all blocks).
__global__ __launch_bounds__(256, 2) void k_gemm1(const float* __restrict__ A, const float* __restrict__ W,
                                                  float* __restrict__ Y, int n){
  __shared__ float As[128*129];
  const int tid = threadIdx.x;
  const int r0 = blockIdx.x * 128;
  {
    int rr = tid >> 5;                // 0..7
    const int k4 = (tid & 31) * 4;
    #pragma unroll
    for (int p = 0; p < 16; ++p, rr += 8){
      int rg = r0 + rr; if (rg > n-1) rg = n-1;
      float4 v = *(const float4*)(A + (size_t)rg*NF + k4);
      float* d = As + rr*129 + k4;
      d[0]=v.x; d[1]=v.y; d[2]=v.z; d[3]=v.w;
    }
  }
  __syncthreads();
  const int tx = tid & 15, ty = tid >> 4;   // 16x16 grid; wave = 4 ty values
  float acc[8][8] = {};
  #pragma unroll 2
  for (int k = 0; k < 128; ++k){
    float a[8];
    #pragma unroll
    for (int i = 0; i < 8; ++i) a[i] = As[(ty*8+i)*129 + k];
    float4 b0 = *(const float4*)(W + k*NF + tx*8);
    float4 b1 = *(const float4*)(W + k*NF + tx*8 + 4);
    #pragma unroll
    for (int i = 0; i < 8; ++i){
      acc[i][0] = fmaf(a[i], b0.x, acc[i][0]); acc[i][1] = fmaf(a[i], b0.y, acc[i][1]);
      acc[i][2] = fmaf(a[i], b0.z, acc[i][2]); acc[i][3] = fmaf(a[i], b0.w, acc[i][3]);
      acc[i][4] = fmaf(a[i], b1.x, acc[i][4]); acc[i][5] = fmaf(a[i], b1.y, acc[i][5]);
      acc[i][6] = fmaf(a[i], b1.z, acc[i][6]); acc[i][7] = fmaf(a[i], b1.w, acc[i][7]);
    }
  }
  #pragma unroll
  for (int i = 0; i < 8; ++i){
    int rg = r0 + ty*8 + i;
    if (rg < n){
      *(float4*)(Y + (size_t)rg*NF + tx*8)     = make_float4(acc[i][0], acc[i][1], acc[i][2], acc[i][3]);
      *(float4*)(Y + (size_t)rg*NF + tx*8 + 4) = make_float4(acc[i][4], acc[i][5], acc[i][6], acc[i][7]);
    }
  }
}

// ---------- GEMM2: G = H @ W1  (n x 128 @ 128 x 64), micro 8x4 ----------
__global__ __launch_bounds__(256, 2) void k_gemm2(const float* __restrict__ A, const float* __restrict__ W,
                                                  float* __restrict__ G, int n){
  __shared__ float As[128*129];
  const int tid = threadIdx.x;
  const int r0 = blockIdx.x * 128;
  {
    int rr = tid >> 5;
    const int k4 = (tid & 31) * 4;
    #pragma unroll
    for (int p = 0; p < 16; ++p, rr += 8){
      int rg = r0 + rr; if (rg > n-1) rg = n-1;
      float4 v = *(const float4*)(A + (size_t)rg*NF + k4);
      float* d = As + rr*129 + k4;
      d[0]=v.x; d[1]=v.y; d[2]=v.z; d[3]=v.w;
    }
  }
  __syncthreads();
  const int tx = tid & 15, ty = tid >> 4;
  float acc[8][4] = {};
  #pragma unroll 2
  for (int k = 0; k < 128; ++k){
    float a[8];
    #pragma unroll
    for (int i = 0; i < 8; ++i) a[i] = As[(ty*8+i)*129 + k];
    float4 b = *(const float4*)(W + k*NC + tx*4);
    #pragma unroll
    for (int i = 0; i < 8; ++i){
      acc[i][0] = fmaf(a[i], b.x, acc[i][0]); acc[i][1] = fmaf(a[i], b.y, acc[i][1]);
      acc[i][2] = fmaf(a[i], b.z, acc[i][2]); acc[i][3] = fmaf(a[i], b.w, acc[i][3]);
    }
  }
  #pragma unroll
  for (int i = 0; i < 8; ++i){
    int rg = r0 + ty*8 + i;
    if (rg < n)
      *(float4*)(G + (size_t)rg*NC + tx*4) = make_float4(acc[i][0], acc[i][1], acc[i][2], acc[i][3]);
  }
}

// ---------- SpMM1 + bias + ReLU: h = relu(spmm(y) + b0), 512B rows ----------
__global__ __launch_bounds__(256) void k_spmm_relu(const float* __restrict__ y, const int2* __restrict__ csr,
    const int* __restrict__ off, const float* __restrict__ bias, float* __restrict__ h, int n){
  int wid  = (blockIdx.x * 256 + threadIdx.x) >> 6;
  int lane = threadIdx.x & 63;
  if (wid >= n) return;
  int s = off[wid], e = off[wid+1];
  float ax = 0.f, ay = 0.f;
  for (int j = s; j < e; ++j){
    int2 ed = csr[j];                         // wave-uniform -> broadcast
    float w = __int_as_float(ed.y);
    float2 v = ((const float2*)(y + (size_t)ed.x * NF))[lane];
    ax = fmaf(w, v.x, ax);
    ay = fmaf(w, v.y, ay);
  }
  float2 bb = ((const float2*)bias)[lane];
  ((float2*)(h + (size_t)wid * NF))[lane] = make_float2(fmaxf(ax+bb.x, 0.f), fmaxf(ay+bb.y, 0.f));
}

// ---------- SpMM2 + bias + log_softmax: out = ls(spmm(g) + b1), 256B rows, lane==class ----------
__global__ __launch_bounds__(256) void k_spmm_ls(const float* __restrict__ g, const int2* __restrict__ csr,
    const int* __restrict__ off, const float* __restrict__ bias, float* __restrict__ out, int n){
  int wid  = (blockIdx.x * 256 + threadIdx.x) >> 6;
  int lane = threadIdx.x & 63;
  if (wid >= n) return;
  int s = off[wid], e = off[wid+1];
  float z = 0.f;
  for (int j = s; j < e; ++j){
    int2 ed = csr[j];
    float w = __int_as_float(ed.y);
    z = fmaf(w, g[(size_t)ed.x * NC + lane], z);
  }
  z += bias[lane];
  float m = z;
  for (int o = 32; o; o >>= 1) m = fmaxf(m, __shfl_xor(m, o));
  float sum = expf(z - m);
  for (int o = 32; o; o >>= 1) sum += __shfl_xor(sum, o);
  out[(size_t)wid * NC + lane] = z - m - logf(sum);
}

extern "C" void kernel_launch(void* const* d_in, const int* in_sizes, int n_in,
                              void* d_out, int out_size, void* d_ws, size_t ws_size,
                              hipStream_t stream){
  const float* x  = (const float*)d_in[0];
  const int* esrc = (const int*)d_in[1];
  const int* edst = (const int*)d_in[2];
  const float* ew = (const float*)d_in[3];
  const float* W0 = (const float*)d_in[4];
  const float* b0 = (const float*)d_in[5];
  const float* W1 = (const float*)d_in[6];
  const float* b1 = (const float*)d_in[7];
  float* out = (float*)d_out;

  const int N = in_sizes[0] / NF;
  const int E = in_sizes[1];

  char* ws = (char*)d_ws;
  size_t o = 0;
  int*  deg  = (int*) (ws + o); o = alignup(o + (size_t)N*4);
  int*  off  = (int*) (ws + o); o = alignup(o + (size_t)(N+1)*4);
  int*  cnt  = (int*) (ws + o); o = alignup(o + (size_t)N*4);
  int*  bsum = (int*) (ws + o); o = alignup(o + 4096);
  int*  boff = (int*) (ws + o); o = alignup(o + 4096);
  int2* csr  = (int2*)(ws + o); o = alignup(o + (size_t)E*8);
  float* y   = (float*)(ws + o); o = alignup(o + (size_t)N*NF*4);  // x@W0; later reused as g = h@W1
  float* h   = (float*)(ws + o); o = alignup(o + (size_t)N*NF*4);
  float* g   = y;  // y is dead after k_spmm_relu

  hipMemsetAsync(deg, 0, (size_t)N*4, stream);
  hipMemsetAsync(cnt, 0, (size_t)N*4, stream);

  const int eb = (E + 255)/256;
  const int nb = (N + 255)/256;   // 391 <= 512 -> single-block scanB

  k_count<<<eb, 256, 0, stream>>>(edst, deg, E);
  k_scanA<<<nb, 256, 0, stream>>>(deg, off, bsum, N);
  k_scanB<<<1, 512, 0, stream>>>(bsum, boff, nb, off, N);
  k_scanC<<<nb, 256, 0, stream>>>(deg, off, boff, N);
  k_fill<<<eb, 256, 0, stream>>>(esrc, edst, ew, off, cnt, csr, E);

  const int gb = (N + 127)/128;
  const int sb = (N + 3)/4;       // 1 node per wave, 4 waves/block

  k_gemm1<<<gb, 256, 0, stream>>>(x, W0, y, N);            // y = x @ W0
  k_spmm_relu<<<sb, 256, 0, stream>>>(y, csr, off, b0, h, N); // h = relu(A y + b0)
  k_gemm2<<<gb, 256, 0, stream>>>(h, W1, g, N);            // g = h @ W1
  k_spmm_ls<<<sb, 256, 0, stream>>>(g, csr, off, b1, out, N); // out = log_softmax(A g + b1)
}

// Round 3
// 500.024 us; speedup vs baseline: 1.6982x; 1.2497x over previous
//
#include <hip/hip_runtime.h>

#define NF 128
#define NC 64

static inline size_t alignup(size_t x){ return (x + 255) & ~(size_t)255; }

// ---------- CSR build ----------
__global__ void k_count(const int* __restrict__ dst, int* __restrict__ deg, int E){
  int i = blockIdx.x*256 + threadIdx.x;
  if (i < E) atomicAdd(&deg[dst[i]], 1);
}

__global__ void k_scanA(const int* __restrict__ deg, int* __restrict__ off, int* __restrict__ bsum, int n){
  __shared__ int sh[256];
  int t = threadIdx.x;
  int i = blockIdx.x*256 + t;
  int v = (i < n) ? deg[i] : 0;
  sh[t] = v; __syncthreads();
  for (int o = 1; o < 256; o <<= 1){
    int u = (t >= o) ? sh[t-o] : 0;
    __syncthreads();
    sh[t] += u;
    __syncthreads();
  }
  if (i < n) off[i] = sh[t];
  if (t == 255) bsum[blockIdx.x] = sh[255];
}

__global__ void k_scanB(const int* __restrict__ bsum, int* __restrict__ boff, int nb, int* __restrict__ off, int n){
  __shared__ int sh[512];
  int t = threadIdx.x;
  int v = (t < nb) ? bsum[t] : 0;
  sh[t] = v; __syncthreads();
  for (int o = 1; o < 512; o <<= 1){
    int u = (t >= o) ? sh[t-o] : 0;
    __syncthreads();
    sh[t] += u;
    __syncthreads();
  }
  if (t < nb) boff[t] = sh[t] - v;
  if (t == nb-1) off[n] = sh[t];
}

__global__ void k_scanC(const int* __restrict__ deg, int* __restrict__ off, const int* __restrict__ boff, int n){
  int i = blockIdx.x*256 + threadIdx.x;
  if (i < n) off[i] = off[i] - deg[i] + boff[blockIdx.x];
}

__global__ void k_fill(const int* __restrict__ src, const int* __restrict__ dst, const float* __restrict__ w,
                       const int* __restrict__ off, int* __restrict__ cnt, int2* __restrict__ csr, int E){
  int i = blockIdx.x*256 + threadIdx.x;
  if (i >= E) return;
  int d = dst[i];
  int p = off[d] + atomicAdd(&cnt[d], 1);
  csr[p] = make_int2(src[i], __float_as_int(w[i]));
}

// ---------- GEMM1: Y = A @ W  (n x 128 @ 128 x 128), register-tiled ----------
__global__ __launch_bounds__(256, 2) void k_gemm1(const float* __restrict__ A, const float* __restrict__ W,
                                                  float* __restrict__ Y, int n){
  __shared__ float As[128*129];
  const int tid = threadIdx.x;
  const int r0 = blockIdx.x * 128;
  {
    int rr = tid >> 5;
    const int k4 = (tid & 31) * 4;
    #pragma unroll
    for (int p = 0; p < 16; ++p, rr += 8){
      int rg = r0 + rr; if (rg > n-1) rg = n-1;
      float4 v = *(const float4*)(A + (size_t)rg*NF + k4);
      float* d = As + rr*129 + k4;
      d[0]=v.x; d[1]=v.y; d[2]=v.z; d[3]=v.w;
    }
  }
  __syncthreads();
  const int tx = tid & 15, ty = tid >> 4;
  float acc[8][8] = {};
  #pragma unroll 2
  for (int k = 0; k < 128; ++k){
    float a[8];
    #pragma unroll
    for (int i = 0; i < 8; ++i) a[i] = As[(ty*8+i)*129 + k];
    float4 b0 = *(const float4*)(W + k*NF + tx*8);
    float4 b1 = *(const float4*)(W + k*NF + tx*8 + 4);
    #pragma unroll
    for (int i = 0; i < 8; ++i){
      acc[i][0] = fmaf(a[i], b0.x, acc[i][0]); acc[i][1] = fmaf(a[i], b0.y, acc[i][1]);
      acc[i][2] = fmaf(a[i], b0.z, acc[i][2]); acc[i][3] = fmaf(a[i], b0.w, acc[i][3]);
      acc[i][4] = fmaf(a[i], b1.x, acc[i][4]); acc[i][5] = fmaf(a[i], b1.y, acc[i][5]);
      acc[i][6] = fmaf(a[i], b1.z, acc[i][6]); acc[i][7] = fmaf(a[i], b1.w, acc[i][7]);
    }
  }
  #pragma unroll
  for (int i = 0; i < 8; ++i){
    int rg = r0 + ty*8 + i;
    if (rg < n){
      *(float4*)(Y + (size_t)rg*NF + tx*8)     = make_float4(acc[i][0], acc[i][1], acc[i][2], acc[i][3]);
      *(float4*)(Y + (size_t)rg*NF + tx*8 + 4) = make_float4(acc[i][4], acc[i][5], acc[i][6], acc[i][7]);
    }
  }
}

// ---------- GEMM2: G = H @ W1  (n x 128 @ 128 x 64), micro 8x4 ----------
__global__ __launch_bounds__(256, 2) void k_gemm2(const float* __restrict__ A, const float* __restrict__ W,
                                                  float* __restrict__ G, int n){
  __shared__ float As[128*129];
  const int tid = threadIdx.x;
  const int r0 = blockIdx.x * 128;
  {
    int rr = tid >> 5;
    const int k4 = (tid & 31) * 4;
    #pragma unroll
    for (int p = 0; p < 16; ++p, rr += 8){
      int rg = r0 + rr; if (rg > n-1) rg = n-1;
      float4 v = *(const float4*)(A + (size_t)rg*NF + k4);
      float* d = As + rr*129 + k4;
      d[0]=v.x; d[1]=v.y; d[2]=v.z; d[3]=v.w;
    }
  }
  __syncthreads();
  const int tx = tid & 15, ty = tid >> 4;
  float acc[8][4] = {};
  #pragma unroll 2
  for (int k = 0; k < 128; ++k){
    float a[8];
    #pragma unroll
    for (int i = 0; i < 8; ++i) a[i] = As[(ty*8+i)*129 + k];
    float4 b = *(const float4*)(W + k*NC + tx*4);
    #pragma unroll
    for (int i = 0; i < 8; ++i){
      acc[i][0] = fmaf(a[i], b.x, acc[i][0]); acc[i][1] = fmaf(a[i], b.y, acc[i][1]);
      acc[i][2] = fmaf(a[i], b.z, acc[i][2]); acc[i][3] = fmaf(a[i], b.w, acc[i][3]);
    }
  }
  #pragma unroll
  for (int i = 0; i < 8; ++i){
    int rg = r0 + ty*8 + i;
    if (rg < n)
      *(float4*)(G + (size_t)rg*NC + tx*4) = make_float4(acc[i][0], acc[i][1], acc[i][2], acc[i][3]);
  }
}

// ---------- SpMM1 + bias + ReLU, 4-edge unrolled gather (4x MLP) ----------
__global__ __launch_bounds__(256) void k_spmm_relu(const float* __restrict__ y, const int2* __restrict__ csr,
    const int* __restrict__ off, const float* __restrict__ bias, float* __restrict__ h, int n){
  int wid  = (blockIdx.x * 256 + threadIdx.x) >> 6;
  int lane = threadIdx.x & 63;
  if (wid >= n) return;
  int s = off[wid], e = off[wid+1];
  float ax0=0.f, ay0=0.f, ax1=0.f, ay1=0.f, ax2=0.f, ay2=0.f, ax3=0.f, ay3=0.f;
  int j = s;
  for (; j + 3 < e; j += 4){
    int2 e0 = csr[j], e1 = csr[j+1], e2 = csr[j+2], e3 = csr[j+3];
    float2 v0 = ((const float2*)(y + (size_t)e0.x * NF))[lane];
    float2 v1 = ((const float2*)(y + (size_t)e1.x * NF))[lane];
    float2 v2 = ((const float2*)(y + (size_t)e2.x * NF))[lane];
    float2 v3 = ((const float2*)(y + (size_t)e3.x * NF))[lane];
    float w0 = __int_as_float(e0.y), w1 = __int_as_float(e1.y);
    float w2 = __int_as_float(e2.y), w3 = __int_as_float(e3.y);
    ax0 = fmaf(w0, v0.x, ax0); ay0 = fmaf(w0, v0.y, ay0);
    ax1 = fmaf(w1, v1.x, ax1); ay1 = fmaf(w1, v1.y, ay1);
    ax2 = fmaf(w2, v2.x, ax2); ay2 = fmaf(w2, v2.y, ay2);
    ax3 = fmaf(w3, v3.x, ax3); ay3 = fmaf(w3, v3.y, ay3);
  }
  for (; j < e; ++j){
    int2 ed = csr[j];
    float w = __int_as_float(ed.y);
    float2 v = ((const float2*)(y + (size_t)ed.x * NF))[lane];
    ax0 = fmaf(w, v.x, ax0); ay0 = fmaf(w, v.y, ay0);
  }
  float ax = (ax0 + ax1) + (ax2 + ax3);
  float ay = (ay0 + ay1) + (ay2 + ay3);
  float2 bb = ((const float2*)bias)[lane];
  ((float2*)(h + (size_t)wid * NF))[lane] = make_float2(fmaxf(ax+bb.x, 0.f), fmaxf(ay+bb.y, 0.f));
}

// ---------- SpMM2 + bias + log_softmax, 4-edge unrolled, lane==class ----------
__global__ __launch_bounds__(256) void k_spmm_ls(const float* __restrict__ g, const int2* __restrict__ csr,
    const int* __restrict__ off, const float* __restrict__ bias, float* __restrict__ out, int n){
  int wid  = (blockIdx.x * 256 + threadIdx.x) >> 6;
  int lane = threadIdx.x & 63;
  if (wid >= n) return;
  int s = off[wid], e = off[wid+1];
  float z0=0.f, z1=0.f, z2=0.f, z3=0.f;
  int j = s;
  for (; j + 3 < e; j += 4){
    int2 e0 = csr[j], e1 = csr[j+1], e2 = csr[j+2], e3 = csr[j+3];
    float v0 = g[(size_t)e0.x * NC + lane];
    float v1 = g[(size_t)e1.x * NC + lane];
    float v2 = g[(size_t)e2.x * NC + lane];
    float v3 = g[(size_t)e3.x * NC + lane];
    z0 = fmaf(__int_as_float(e0.y), v0, z0);
    z1 = fmaf(__int_as_float(e1.y), v1, z1);
    z2 = fmaf(__int_as_float(e2.y), v2, z2);
    z3 = fmaf(__int_as_float(e3.y), v3, z3);
  }
  for (; j < e; ++j){
    int2 ed = csr[j];
    z0 = fmaf(__int_as_float(ed.y), g[(size_t)ed.x * NC + lane], z0);
  }
  float z = (z0 + z1) + (z2 + z3);
  z += bias[lane];
  float m = z;
  for (int o = 32; o; o >>= 1) m = fmaxf(m, __shfl_xor(m, o));
  float sum = expf(z - m);
  for (int o = 32; o; o >>= 1) sum += __shfl_xor(sum, o);
  out[(size_t)wid * NC + lane] = z - m - logf(sum);
}

extern "C" void kernel_launch(void* const* d_in, const int* in_sizes, int n_in,
                              void* d_out, int out_size, void* d_ws, size_t ws_size,
                              hipStream_t stream){
  const float* x  = (const float*)d_in[0];
  const int* esrc = (const int*)d_in[1];
  const int* edst = (const int*)d_in[2];
  const float* ew = (const float*)d_in[3];
  const float* W0 = (const float*)d_in[4];
  const float* b0 = (const float*)d_in[5];
  const float* W1 = (const float*)d_in[6];
  const float* b1 = (const float*)d_in[7];
  float* out = (float*)d_out;

  const int N = in_sizes[0] / NF;
  const int E = in_sizes[1];

  char* ws = (char*)d_ws;
  size_t o = 0;
  int*  deg  = (int*) (ws + o); o = alignup(o + (size_t)N*4);
  int*  off  = (int*) (ws + o); o = alignup(o + (size_t)(N+1)*4);
  int*  cnt  = (int*) (ws + o); o = alignup(o + (size_t)N*4);
  int*  bsum = (int*) (ws + o); o = alignup(o + 4096);
  int*  boff = (int*) (ws + o); o = alignup(o + 4096);
  int2* csr  = (int2*)(ws + o); o = alignup(o + (size_t)E*8);
  float* y   = (float*)(ws + o); o = alignup(o + (size_t)N*NF*4);  // x@W0; later reused as g = h@W1
  float* h   = (float*)(ws + o); o = alignup(o + (size_t)N*NF*4);
  float* g   = y;  // y dead after k_spmm_relu

  hipMemsetAsync(deg, 0, (size_t)N*4, stream);
  hipMemsetAsync(cnt, 0, (size_t)N*4, stream);

  const int eb = (E + 255)/256;
  const int nb = (N + 255)/256;

  k_count<<<eb, 256, 0, stream>>>(edst, deg, E);
  k_scanA<<<nb, 256, 0, stream>>>(deg, off, bsum, N);
  k_scanB<<<1, 512, 0, stream>>>(bsum, boff, nb, off, N);
  k_scanC<<<nb, 256, 0, stream>>>(deg, off, boff, N);
  k_fill<<<eb, 256, 0, stream>>>(esrc, edst, ew, off, cnt, csr, E);

  const int gb = (N + 127)/128;
  const int sb = (N + 3)/4;

  k_gemm1<<<gb, 256, 0, stream>>>(x, W0, y, N);               // y = x @ W0
  k_spmm_relu<<<sb, 256, 0, stream>>>(y, csr, off, b0, h, N); // h = relu(A y + b0)
  k_gemm2<<<gb, 256, 0, stream>>>(h, W1, g, N);               // g = h @ W1
  k_spmm_ls<<<sb, 256, 0, stream>>>(g, csr, off, b1, out, N); // out = log_softmax(A g + b1)
}

// Round 4
// 437.532 us; speedup vs baseline: 1.9408x; 1.1428x over previous
//
#include <hip/hip_runtime.h>

#define NF 128
#define NC 64

static inline size_t alignup(size_t x){ return (x + 255) & ~(size_t)255; }

__device__ __forceinline__ unsigned short f2bf(float f){
  unsigned u = __float_as_uint(f);
  u += 0x7fffu + ((u >> 16) & 1u);       // round-to-nearest-even
  return (unsigned short)(u >> 16);
}
__device__ __forceinline__ float bflo(unsigned u){ return __uint_as_float(u << 16); }
__device__ __forceinline__ float bfhi(unsigned u){ return __uint_as_float(u & 0xffff0000u); }

// ---------- CSR build ----------
__global__ void k_count(const int* __restrict__ dst, int* __restrict__ deg, int E){
  int i = blockIdx.x*256 + threadIdx.x;
  if (i < E) atomicAdd(&deg[dst[i]], 1);
}

__global__ void k_scanA(const int* __restrict__ deg, int* __restrict__ off, int* __restrict__ bsum, int n){
  __shared__ int sh[256];
  int t = threadIdx.x;
  int i = blockIdx.x*256 + t;
  int v = (i < n) ? deg[i] : 0;
  sh[t] = v; __syncthreads();
  for (int o = 1; o < 256; o <<= 1){
    int u = (t >= o) ? sh[t-o] : 0;
    __syncthreads();
    sh[t] += u;
    __syncthreads();
  }
  if (i < n) off[i] = sh[t];
  if (t == 255) bsum[blockIdx.x] = sh[255];
}

__global__ void k_scanB(const int* __restrict__ bsum, int* __restrict__ boff, int nb, int* __restrict__ off, int n){
  __shared__ int sh[512];
  int t = threadIdx.x;
  int v = (t < nb) ? bsum[t] : 0;
  sh[t] = v; __syncthreads();
  for (int o = 1; o < 512; o <<= 1){
    int u = (t >= o) ? sh[t-o] : 0;
    __syncthreads();
    sh[t] += u;
    __syncthreads();
  }
  if (t < nb) boff[t] = sh[t] - v;
  if (t == nb-1) off[n] = sh[t];
}

__global__ void k_scanC(const int* __restrict__ deg, int* __restrict__ off, const int* __restrict__ boff, int n){
  int i = blockIdx.x*256 + threadIdx.x;
  if (i < n) off[i] = off[i] - deg[i] + boff[blockIdx.x];
}

__global__ void k_fill(const int* __restrict__ src, const int* __restrict__ dst, const float* __restrict__ w,
                       const int* __restrict__ off, int* __restrict__ cnt, int2* __restrict__ csr, int E){
  int i = blockIdx.x*256 + threadIdx.x;
  if (i >= E) return;
  int d = dst[i];
  int p = off[d] + atomicAdd(&cnt[d], 1);
  csr[p] = make_int2(src[i], __float_as_int(w[i]));
}

// ---------- GEMM1: Y(bf16) = A @ W  (n x 128 @ 128 x 128) ----------
__global__ __launch_bounds__(256, 2) void k_gemm1(const float* __restrict__ A, const float* __restrict__ W,
                                                  unsigned short* __restrict__ Y, int n){
  __shared__ float As[128*129];
  const int tid = threadIdx.x;
  const int r0 = blockIdx.x * 128;
  {
    int rr = tid >> 5;
    const int k4 = (tid & 31) * 4;
    #pragma unroll
    for (int p = 0; p < 16; ++p, rr += 8){
      int rg = r0 + rr; if (rg > n-1) rg = n-1;
      float4 v = *(const float4*)(A + (size_t)rg*NF + k4);
      float* d = As + rr*129 + k4;
      d[0]=v.x; d[1]=v.y; d[2]=v.z; d[3]=v.w;
    }
  }
  __syncthreads();
  const int tx = tid & 15, ty = tid >> 4;
  float acc[8][8] = {};
  #pragma unroll 2
  for (int k = 0; k < 128; ++k){
    float a[8];
    #pragma unroll
    for (int i = 0; i < 8; ++i) a[i] = As[(ty*8+i)*129 + k];
    float4 b0 = *(const float4*)(W + k*NF + tx*8);
    float4 b1 = *(const float4*)(W + k*NF + tx*8 + 4);
    #pragma unroll
    for (int i = 0; i < 8; ++i){
      acc[i][0] = fmaf(a[i], b0.x, acc[i][0]); acc[i][1] = fmaf(a[i], b0.y, acc[i][1]);
      acc[i][2] = fmaf(a[i], b0.z, acc[i][2]); acc[i][3] = fmaf(a[i], b0.w, acc[i][3]);
      acc[i][4] = fmaf(a[i], b1.x, acc[i][4]); acc[i][5] = fmaf(a[i], b1.y, acc[i][5]);
      acc[i][6] = fmaf(a[i], b1.z, acc[i][6]); acc[i][7] = fmaf(a[i], b1.w, acc[i][7]);
    }
  }
  #pragma unroll
  for (int i = 0; i < 8; ++i){
    int rg = r0 + ty*8 + i;
    if (rg < n){
      uint4 p;
      p.x = (unsigned)f2bf(acc[i][0]) | ((unsigned)f2bf(acc[i][1]) << 16);
      p.y = (unsigned)f2bf(acc[i][2]) | ((unsigned)f2bf(acc[i][3]) << 16);
      p.z = (unsigned)f2bf(acc[i][4]) | ((unsigned)f2bf(acc[i][5]) << 16);
      p.w = (unsigned)f2bf(acc[i][6]) | ((unsigned)f2bf(acc[i][7]) << 16);
      *(uint4*)(Y + (size_t)rg*NF + tx*8) = p;
    }
  }
}

// ---------- GEMM2: G(bf16) = H @ W1  (n x 128 @ 128 x 64) ----------
__global__ __launch_bounds__(256, 2) void k_gemm2(const float* __restrict__ A, const float* __restrict__ W,
                                                  unsigned short* __restrict__ G, int n){
  __shared__ float As[128*129];
  const int tid = threadIdx.x;
  const int r0 = blockIdx.x * 128;
  {
    int rr = tid >> 5;
    const int k4 = (tid & 31) * 4;
    #pragma unroll
    for (int p = 0; p < 16; ++p, rr += 8){
      int rg = r0 + rr; if (rg > n-1) rg = n-1;
      float4 v = *(const float4*)(A + (size_t)rg*NF + k4);
      float* d = As + rr*129 + k4;
      d[0]=v.x; d[1]=v.y; d[2]=v.z; d[3]=v.w;
    }
  }
  __syncthreads();
  const int tx = tid & 15, ty = tid >> 4;
  float acc[8][4] = {};
  #pragma unroll 2
  for (int k = 0; k < 128; ++k){
    float a[8];
    #pragma unroll
    for (int i = 0; i < 8; ++i) a[i] = As[(ty*8+i)*129 + k];
    float4 b = *(const float4*)(W + k*NC + tx*4);
    #pragma unroll
    for (int i = 0; i < 8; ++i){
      acc[i][0] = fmaf(a[i], b.x, acc[i][0]); acc[i][1] = fmaf(a[i], b.y, acc[i][1]);
      acc[i][2] = fmaf(a[i], b.z, acc[i][2]); acc[i][3] = fmaf(a[i], b.w, acc[i][3]);
    }
  }
  #pragma unroll
  for (int i = 0; i < 8; ++i){
    int rg = r0 + ty*8 + i;
    if (rg < n){
      uint2 p;
      p.x = (unsigned)f2bf(acc[i][0]) | ((unsigned)f2bf(acc[i][1]) << 16);
      p.y = (unsigned)f2bf(acc[i][2]) | ((unsigned)f2bf(acc[i][3]) << 16);
      *(uint2*)(G + (size_t)rg*NC + tx*4) = p;
    }
  }
}

// ---------- SpMM1 + bias + ReLU: h = relu(A@y + b0); y bf16, 8-deep MLP ----------
__global__ __launch_bounds__(256) void k_spmm_relu(const unsigned short* __restrict__ y, const int2* __restrict__ csr,
    const int* __restrict__ off, const float* __restrict__ bias, float* __restrict__ h, int n){
  int wid  = (blockIdx.x * 256 + threadIdx.x) >> 6;
  int lane = threadIdx.x & 63;
  if (wid >= n) return;
  int s = off[wid], e = off[wid+1];
  float ax[8], ay[8];
  #pragma unroll
  for (int k = 0; k < 8; ++k){ ax[k] = 0.f; ay[k] = 0.f; }
  for (int j = s; j < e; j += 8){
    int2 ed[8];
    #pragma unroll
    for (int k = 0; k < 8; ++k){
      int id = j + k; if (id > e-1) id = e-1;
      ed[k] = csr[id];                               // wave-uniform -> broadcast
    }
    unsigned v[8];
    #pragma unroll
    for (int k = 0; k < 8; ++k)
      v[k] = ((const unsigned*)(y + (size_t)ed[k].x * NF))[lane];   // 256B coalesced bf16 row
    #pragma unroll
    for (int k = 0; k < 8; ++k){
      float w = (j + k < e) ? __int_as_float(ed[k].y) : 0.f;
      ax[k] = fmaf(w, bflo(v[k]), ax[k]);
      ay[k] = fmaf(w, bfhi(v[k]), ay[k]);
    }
  }
  float sx = ((ax[0]+ax[1]) + (ax[2]+ax[3])) + ((ax[4]+ax[5]) + (ax[6]+ax[7]));
  float sy = ((ay[0]+ay[1]) + (ay[2]+ay[3])) + ((ay[4]+ay[5]) + (ay[6]+ay[7]));
  float2 bb = ((const float2*)bias)[lane];
  ((float2*)(h + (size_t)wid * NF))[lane] = make_float2(fmaxf(sx+bb.x, 0.f), fmaxf(sy+bb.y, 0.f));
}

// ---------- SpMM2 + bias + log_softmax: out = ls(A@g + b1); g bf16, lane==class ----------
__global__ __launch_bounds__(256) void k_spmm_ls(const unsigned short* __restrict__ g, const int2* __restrict__ csr,
    const int* __restrict__ off, const float* __restrict__ bias, float* __restrict__ out, int n){
  int wid  = (blockIdx.x * 256 + threadIdx.x) >> 6;
  int lane = threadIdx.x & 63;
  if (wid >= n) return;
  int s = off[wid], e = off[wid+1];
  float z[8];
  #pragma unroll
  for (int k = 0; k < 8; ++k) z[k] = 0.f;
  for (int j = s; j < e; j += 8){
    int2 ed[8];
    #pragma unroll
    for (int k = 0; k < 8; ++k){
      int id = j + k; if (id > e-1) id = e-1;
      ed[k] = csr[id];
    }
    unsigned short v[8];
    #pragma unroll
    for (int k = 0; k < 8; ++k)
      v[k] = (g + (size_t)ed[k].x * NC)[lane];       // 128B coalesced bf16 row
    #pragma unroll
    for (int k = 0; k < 8; ++k){
      float w = (j + k < e) ? __int_as_float(ed[k].y) : 0.f;
      z[k] = fmaf(w, bflo((unsigned)v[k]), z[k]);
    }
  }
  float zz = ((z[0]+z[1]) + (z[2]+z[3])) + ((z[4]+z[5]) + (z[6]+z[7]));
  zz += bias[lane];
  float m = zz;
  for (int o = 32; o; o >>= 1) m = fmaxf(m, __shfl_xor(m, o));
  float sum = expf(zz - m);
  for (int o = 32; o; o >>= 1) sum += __shfl_xor(sum, o);
  out[(size_t)wid * NC + lane] = zz - m - logf(sum);
}

extern "C" void kernel_launch(void* const* d_in, const int* in_sizes, int n_in,
                              void* d_out, int out_size, void* d_ws, size_t ws_size,
                              hipStream_t stream){
  const float* x  = (const float*)d_in[0];
  const int* esrc = (const int*)d_in[1];
  const int* edst = (const int*)d_in[2];
  const float* ew = (const float*)d_in[3];
  const float* W0 = (const float*)d_in[4];
  const float* b0 = (const float*)d_in[5];
  const float* W1 = (const float*)d_in[6];
  const float* b1 = (const float*)d_in[7];
  float* out = (float*)d_out;

  const int N = in_sizes[0] / NF;
  const int E = in_sizes[1];

  char* ws = (char*)d_ws;
  size_t o = 0;
  int*  deg  = (int*) (ws + o); o = alignup(o + (size_t)N*4);
  int*  off  = (int*) (ws + o); o = alignup(o + (size_t)(N+1)*4);
  int*  cnt  = (int*) (ws + o); o = alignup(o + (size_t)N*4);
  int*  bsum = (int*) (ws + o); o = alignup(o + 4096);
  int*  boff = (int*) (ws + o); o = alignup(o + 4096);
  int2* csr  = (int2*)(ws + o); o = alignup(o + (size_t)E*8);
  unsigned short* y = (unsigned short*)(ws + o); o = alignup(o + (size_t)N*NF*2);  // bf16; reused as g
  float* h   = (float*)(ws + o); o = alignup(o + (size_t)N*NF*4);
  unsigned short* g = y;  // y dead after k_spmm_relu

  hipMemsetAsync(deg, 0, (size_t)N*4, stream);
  hipMemsetAsync(cnt, 0, (size_t)N*4, stream);

  const int eb = (E + 255)/256;
  const int nb = (N + 255)/256;

  k_count<<<eb, 256, 0, stream>>>(edst, deg, E);
  k_scanA<<<nb, 256, 0, stream>>>(deg, off, bsum, N);
  k_scanB<<<1, 512, 0, stream>>>(bsum, boff, nb, off, N);
  k_scanC<<<nb, 256, 0, stream>>>(deg, off, boff, N);
  k_fill<<<eb, 256, 0, stream>>>(esrc, edst, ew, off, cnt, csr, E);

  const int gb = (N + 127)/128;
  const int sb = (N + 3)/4;

  k_gemm1<<<gb, 256, 0, stream>>>(x, W0, y, N);               // y = bf16(x @ W0)
  k_spmm_relu<<<sb, 256, 0, stream>>>(y, csr, off, b0, h, N); // h = relu(A y + b0)
  k_gemm2<<<gb, 256, 0, stream>>>(h, W1, g, N);               // g = bf16(h @ W1)
  k_spmm_ls<<<sb, 256, 0, stream>>>(g, csr, off, b1, out, N); // out = log_softmax(A g + b1)
}

// Round 5
// 359.087 us; speedup vs baseline: 2.3648x; 1.2185x over previous
//
#include <hip/hip_runtime.h>

#define NF 128
#define NC 64
#define NBMAX 512          // max dst-buckets (N/256 = 391 for N=100000)
#define TPART 8192         // edges per k_part block

static inline size_t alignup(size_t x){ return (x + 255) & ~(size_t)255; }

__device__ __forceinline__ unsigned short f2bf(float f){
  unsigned u = __float_as_uint(f);
  u += 0x7fffu + ((u >> 16) & 1u);       // round-to-nearest-even
  return (unsigned short)(u >> 16);
}
__device__ __forceinline__ float bflo(unsigned u){ return __uint_as_float(u << 16); }
__device__ __forceinline__ float bfhi(unsigned u){ return __uint_as_float(u & 0xffff0000u); }

// ---------- 1. bucket histogram (bucket = dst >> 8), LDS-binned ----------
__global__ __launch_bounds__(256) void k_hist(const int* __restrict__ dst, int* __restrict__ bhist, int E, int NB){
  __shared__ int h[NBMAX];
  int t = threadIdx.x;
  for (int i = t; i < NBMAX; i += 256) h[i] = 0;
  __syncthreads();
  int t0 = blockIdx.x * 4096;
  #pragma unroll 4
  for (int k = 0; k < 16; ++k){
    int i = t0 + (k << 8) + t;
    if (i < E) atomicAdd(&h[dst[i] >> 8], 1);
  }
  __syncthreads();
  for (int b = t; b < NB; b += 256) if (h[b]) atomicAdd(&bhist[b], h[b]);
}

// ---------- 2. scan bucket sizes -> bases & cursors; off[N]=E ----------
__global__ __launch_bounds__(512) void k_bscan(const int* __restrict__ bhist, int* __restrict__ bbase,
                                               int* __restrict__ bcur, int* __restrict__ off, int NB, int N){
  __shared__ int sh[512];
  int t = threadIdx.x;
  int v = (t < NB) ? bhist[t] : 0;
  sh[t] = v; __syncthreads();
  for (int o = 1; o < 512; o <<= 1){
    int a = (t >= o) ? sh[t-o] : 0;
    __syncthreads();
    sh[t] += a;
    __syncthreads();
  }
  if (t < NB){ bbase[t] = sh[t] - v; bcur[t] = sh[t] - v; }
  if (t == 511) off[N] = sh[511];
}

// ---------- 3. partition edges into bucket-contiguous runs (LDS staged) ----------
__global__ __launch_bounds__(256) void k_part(const int* __restrict__ src, const int* __restrict__ dst,
    const float* __restrict__ w, int* __restrict__ bcur, int2* __restrict__ part, int E, int NB){
  __shared__ int2 stage[TPART];            // 64 KB
  __shared__ int hist[NBMAX];
  __shared__ int scn[NBMAX];
  __shared__ int cnt2[NBMAX];
  __shared__ int baseg[NBMAX];
  const int t = threadIdx.x;
  const int t0 = blockIdx.x * TPART;
  for (int i = t; i < NBMAX; i += 256){ hist[i] = 0; cnt2[i] = 0; }
  __syncthreads();
  // phase 1: histogram
  #pragma unroll 4
  for (int k = 0; k < 32; ++k){
    int i = t0 + (k << 8) + t;
    if (i < E) atomicAdd(&hist[dst[i] >> 8], 1);
  }
  __syncthreads();
  // phase 2: inclusive scan of hist (512-wide, 2 elems/thread)
  scn[t] = hist[t]; scn[t+256] = hist[t+256];
  __syncthreads();
  for (int o = 1; o < 512; o <<= 1){
    int a0 = (t >= o) ? scn[t-o] : 0;
    int a1 = scn[t+256-o];
    __syncthreads();
    scn[t] += a0; scn[t+256] += a1;
    __syncthreads();
  }
  // phase 3: reserve global runs
  for (int b = t; b < NB; b += 256) baseg[b] = hist[b] ? atomicAdd(&bcur[b], hist[b]) : 0;
  __syncthreads();
  // phase 4: stage records grouped by bucket
  #pragma unroll 4
  for (int k = 0; k < 32; ++k){
    int i = t0 + (k << 8) + t;
    if (i < E){
      int d = dst[i], b = d >> 8;
      int r = atomicAdd(&cnt2[b], 1);
      int pos = scn[b] - hist[b] + r;
      stage[pos] = make_int2(((d & 255) << 17) | src[i], __float_as_int(w[i]));
    }
  }
  __syncthreads();
  // phase 5: coalesced flush, one wave strides buckets
  int wv = t >> 6, ln = t & 63;
  for (int b = wv; b < NB; b += 4){
    int c = hist[b];
    if (!c) continue;
    int lo = scn[b] - c, gb = baseg[b];
    for (int s = ln; s < c; s += 64) part[gb + s] = stage[lo + s];
  }
}

// ---------- 4. exact fill per bucket: off[] + csr[] (L2-window-local) ----------
__global__ __launch_bounds__(256) void k_fill2(const int2* __restrict__ part, const int* __restrict__ bhist,
    const int* __restrict__ bbase, int* __restrict__ off, int2* __restrict__ csr, int N){
  __shared__ int deg[256], scn[256], c2[256];
  const int b = blockIdx.x, t = threadIdx.x;
  const int base = bbase[b], cnt = bhist[b];
  const int d0 = b << 8;
  const int nd = min(256, N - d0);
  deg[t] = 0; c2[t] = 0;
  __syncthreads();
  for (int s = t; s < cnt; s += 256) atomicAdd(&deg[(part[base+s].x >> 17) & 255], 1);
  __syncthreads();
  scn[t] = deg[t];
  __syncthreads();
  for (int o = 1; o < 256; o <<= 1){
    int a = (t >= o) ? scn[t-o] : 0;
    __syncthreads();
    scn[t] += a;
    __syncthreads();
  }
  if (t < nd) off[d0 + t] = base + scn[t] - deg[t];
  __syncthreads();
  for (int s = t; s < cnt; s += 256){
    int2 rec = part[base + s];
    int dl = (rec.x >> 17) & 255;
    int p = base + scn[dl] - deg[dl] + atomicAdd(&c2[dl], 1);
    csr[p] = make_int2(rec.x & 0x1FFFF, rec.y);
  }
}

// ---------- GEMM1: Y(bf16) = A @ W  (n x 128 @ 128 x 128) ----------
__global__ __launch_bounds__(256, 2) void k_gemm1(const float* __restrict__ A, const float* __restrict__ W,
                                                  unsigned short* __restrict__ Y, int n){
  __shared__ float As[128*129];
  const int tid = threadIdx.x;
  const int r0 = blockIdx.x * 128;
  {
    int rr = tid >> 5;
    const int k4 = (tid & 31) * 4;
    #pragma unroll
    for (int p = 0; p < 16; ++p, rr += 8){
      int rg = r0 + rr; if (rg > n-1) rg = n-1;
      float4 v = *(const float4*)(A + (size_t)rg*NF + k4);
      float* d = As + rr*129 + k4;
      d[0]=v.x; d[1]=v.y; d[2]=v.z; d[3]=v.w;
    }
  }
  __syncthreads();
  const int tx = tid & 15, ty = tid >> 4;
  float acc[8][8] = {};
  #pragma unroll 2
  for (int k = 0; k < 128; ++k){
    float a[8];
    #pragma unroll
    for (int i = 0; i < 8; ++i) a[i] = As[(ty*8+i)*129 + k];
    float4 b0 = *(const float4*)(W + k*NF + tx*8);
    float4 b1 = *(const float4*)(W + k*NF + tx*8 + 4);
    #pragma unroll
    for (int i = 0; i < 8; ++i){
      acc[i][0] = fmaf(a[i], b0.x, acc[i][0]); acc[i][1] = fmaf(a[i], b0.y, acc[i][1]);
      acc[i][2] = fmaf(a[i], b0.z, acc[i][2]); acc[i][3] = fmaf(a[i], b0.w, acc[i][3]);
      acc[i][4] = fmaf(a[i], b1.x, acc[i][4]); acc[i][5] = fmaf(a[i], b1.y, acc[i][5]);
      acc[i][6] = fmaf(a[i], b1.z, acc[i][6]); acc[i][7] = fmaf(a[i], b1.w, acc[i][7]);
    }
  }
  #pragma unroll
  for (int i = 0; i < 8; ++i){
    int rg = r0 + ty*8 + i;
    if (rg < n){
      uint4 p;
      p.x = (unsigned)f2bf(acc[i][0]) | ((unsigned)f2bf(acc[i][1]) << 16);
      p.y = (unsigned)f2bf(acc[i][2]) | ((unsigned)f2bf(acc[i][3]) << 16);
      p.z = (unsigned)f2bf(acc[i][4]) | ((unsigned)f2bf(acc[i][5]) << 16);
      p.w = (unsigned)f2bf(acc[i][6]) | ((unsigned)f2bf(acc[i][7]) << 16);
      *(uint4*)(Y + (size_t)rg*NF + tx*8) = p;
    }
  }
}

// ---------- GEMM2: G(bf16) = H @ W1  (n x 128 @ 128 x 64) ----------
__global__ __launch_bounds__(256, 2) void k_gemm2(const float* __restrict__ A, const float* __restrict__ W,
                                                  unsigned short* __restrict__ G, int n){
  __shared__ float As[128*129];
  const int tid = threadIdx.x;
  const int r0 = blockIdx.x * 128;
  {
    int rr = tid >> 5;
    const int k4 = (tid & 31) * 4;
    #pragma unroll
    for (int p = 0; p < 16; ++p, rr += 8){
      int rg = r0 + rr; if (rg > n-1) rg = n-1;
      float4 v = *(const float4*)(A + (size_t)rg*NF + k4);
      float* d = As + rr*129 + k4;
      d[0]=v.x; d[1]=v.y; d[2]=v.z; d[3]=v.w;
    }
  }
  __syncthreads();
  const int tx = tid & 15, ty = tid >> 4;
  float acc[8][4] = {};
  #pragma unroll 2
  for (int k = 0; k < 128; ++k){
    float a[8];
    #pragma unroll
    for (int i = 0; i < 8; ++i) a[i] = As[(ty*8+i)*129 + k];
    float4 b = *(const float4*)(W + k*NC + tx*4);
    #pragma unroll
    for (int i = 0; i < 8; ++i){
      acc[i][0] = fmaf(a[i], b.x, acc[i][0]); acc[i][1] = fmaf(a[i], b.y, acc[i][1]);
      acc[i][2] = fmaf(a[i], b.z, acc[i][2]); acc[i][3] = fmaf(a[i], b.w, acc[i][3]);
    }
  }
  #pragma unroll
  for (int i = 0; i < 8; ++i){
    int rg = r0 + ty*8 + i;
    if (rg < n){
      uint2 p;
      p.x = (unsigned)f2bf(acc[i][0]) | ((unsigned)f2bf(acc[i][1]) << 16);
      p.y = (unsigned)f2bf(acc[i][2]) | ((unsigned)f2bf(acc[i][3]) << 16);
      *(uint2*)(G + (size_t)rg*NC + tx*4) = p;
    }
  }
}

// ---------- SpMM1 + bias + ReLU: h = relu(A@y + b0); y bf16, 8-deep MLP ----------
__global__ __launch_bounds__(256) void k_spmm_relu(const unsigned short* __restrict__ y, const int2* __restrict__ csr,
    const int* __restrict__ off, const float* __restrict__ bias, float* __restrict__ h, int n){
  int wid  = (blockIdx.x * 256 + threadIdx.x) >> 6;
  int lane = threadIdx.x & 63;
  if (wid >= n) return;
  int s = off[wid], e = off[wid+1];
  float ax[8], ay[8];
  #pragma unroll
  for (int k = 0; k < 8; ++k){ ax[k] = 0.f; ay[k] = 0.f; }
  for (int j = s; j < e; j += 8){
    int2 ed[8];
    #pragma unroll
    for (int k = 0; k < 8; ++k){
      int id = j + k; if (id > e-1) id = e-1;
      ed[k] = csr[id];                               // wave-uniform -> broadcast
    }
    unsigned v[8];
    #pragma unroll
    for (int k = 0; k < 8; ++k)
      v[k] = ((const unsigned*)(y + (size_t)ed[k].x * NF))[lane];   // 256B coalesced bf16 row
    #pragma unroll
    for (int k = 0; k < 8; ++k){
      float w = (j + k < e) ? __int_as_float(ed[k].y) : 0.f;
      ax[k] = fmaf(w, bflo(v[k]), ax[k]);
      ay[k] = fmaf(w, bfhi(v[k]), ay[k]);
    }
  }
  float sx = ((ax[0]+ax[1]) + (ax[2]+ax[3])) + ((ax[4]+ax[5]) + (ax[6]+ax[7]));
  float sy = ((ay[0]+ay[1]) + (ay[2]+ay[3])) + ((ay[4]+ay[5]) + (ay[6]+ay[7]));
  float2 bb = ((const float2*)bias)[lane];
  ((float2*)(h + (size_t)wid * NF))[lane] = make_float2(fmaxf(sx+bb.x, 0.f), fmaxf(sy+bb.y, 0.f));
}

// ---------- SpMM2 + bias + log_softmax: out = ls(A@g + b1); g bf16, lane==class ----------
__global__ __launch_bounds__(256) void k_spmm_ls(const unsigned short* __restrict__ g, const int2* __restrict__ csr,
    const int* __restrict__ off, const float* __restrict__ bias, float* __restrict__ out, int n){
  int wid  = (blockIdx.x * 256 + threadIdx.x) >> 6;
  int lane = threadIdx.x & 63;
  if (wid >= n) return;
  int s = off[wid], e = off[wid+1];
  float z[8];
  #pragma unroll
  for (int k = 0; k < 8; ++k) z[k] = 0.f;
  for (int j = s; j < e; j += 8){
    int2 ed[8];
    #pragma unroll
    for (int k = 0; k < 8; ++k){
      int id = j + k; if (id > e-1) id = e-1;
      ed[k] = csr[id];
    }
    unsigned short v[8];
    #pragma unroll
    for (int k = 0; k < 8; ++k)
      v[k] = (g + (size_t)ed[k].x * NC)[lane];       // 128B coalesced bf16 row
    #pragma unroll
    for (int k = 0; k < 8; ++k){
      float w = (j + k < e) ? __int_as_float(ed[k].y) : 0.f;
      z[k] = fmaf(w, bflo((unsigned)v[k]), z[k]);
    }
  }
  float zz = ((z[0]+z[1]) + (z[2]+z[3])) + ((z[4]+z[5]) + (z[6]+z[7]));
  zz += bias[lane];
  float m = zz;
  for (int o = 32; o; o >>= 1) m = fmaxf(m, __shfl_xor(m, o));
  float sum = expf(zz - m);
  for (int o = 32; o; o >>= 1) sum += __shfl_xor(sum, o);
  out[(size_t)wid * NC + lane] = zz - m - logf(sum);
}

extern "C" void kernel_launch(void* const* d_in, const int* in_sizes, int n_in,
                              void* d_out, int out_size, void* d_ws, size_t ws_size,
                              hipStream_t stream){
  const float* x  = (const float*)d_in[0];
  const int* esrc = (const int*)d_in[1];
  const int* edst = (const int*)d_in[2];
  const float* ew = (const float*)d_in[3];
  const float* W0 = (const float*)d_in[4];
  const float* b0 = (const float*)d_in[5];
  const float* W1 = (const float*)d_in[6];
  const float* b1 = (const float*)d_in[7];
  float* out = (float*)d_out;

  const int N = in_sizes[0] / NF;
  const int E = in_sizes[1];
  const int NB = (N + 255) >> 8;            // 391 buckets of 256 dsts

  char* ws = (char*)d_ws;
  size_t o = 0;
  int*  bhist = (int*) (ws + o); o = alignup(o + NBMAX*4);
  int*  bbase = (int*) (ws + o); o = alignup(o + NBMAX*4);
  int*  bcur  = (int*) (ws + o); o = alignup(o + NBMAX*4);
  int*  off   = (int*) (ws + o); o = alignup(o + (size_t)(N+1)*4);
  int2* part  = (int2*)(ws + o); o = alignup(o + (size_t)E*8);
  int2* csr   = (int2*)(ws + o); o = alignup(o + (size_t)E*8);
  unsigned short* y = (unsigned short*)(ws + o); o = alignup(o + (size_t)N*NF*2);  // bf16; reused as g
  float* h    = (float*)(ws + o); o = alignup(o + (size_t)N*NF*4);
  unsigned short* g = y;  // y dead after k_spmm_relu

  hipMemsetAsync(bhist, 0, NBMAX*4, stream);

  const int hb = (E + 4095)/4096;
  const int pb = (E + TPART-1)/TPART;

  k_hist <<<hb, 256, 0, stream>>>(edst, bhist, E, NB);
  k_bscan<<<1, 512, 0, stream>>>(bhist, bbase, bcur, off, NB, N);
  k_part <<<pb, 256, 0, stream>>>(esrc, edst, ew, bcur, part, E, NB);
  k_fill2<<<NB, 256, 0, stream>>>(part, bhist, bbase, off, csr, N);

  const int gb = (N + 127)/128;
  const int sb = (N + 3)/4;

  k_gemm1<<<gb, 256, 0, stream>>>(x, W0, y, N);               // y = bf16(x @ W0)
  k_spmm_relu<<<sb, 256, 0, stream>>>(y, csr, off, b0, h, N); // h = relu(A y + b0)
  k_gemm2<<<gb, 256, 0, stream>>>(h, W1, g, N);               // g = bf16(h @ W1)
  k_spmm_ls<<<sb, 256, 0, stream>>>(g, csr, off, b1, out, N); // out = log_softmax(A g + b1)
}

// Round 6
// 348.218 us; speedup vs baseline: 2.4386x; 1.0312x over previous
//
#include <hip/hip_runtime.h>

#define NF 128
#define NC 64
#define NBMAX 512          // max dst-buckets (N/256 = 391 for N=100000)
#define TPART 8192         // edges per k_part block

static inline size_t alignup(size_t x){ return (x + 255) & ~(size_t)255; }

__device__ __forceinline__ unsigned short f2bf(float f){
  unsigned u = __float_as_uint(f);
  u += 0x7fffu + ((u >> 16) & 1u);       // round-to-nearest-even
  return (unsigned short)(u >> 16);
}
__device__ __forceinline__ float bflo(unsigned u){ return __uint_as_float(u << 16); }
__device__ __forceinline__ float bfhi(unsigned u){ return __uint_as_float(u & 0xffff0000u); }

// ---------- 1. bucket histogram (bucket = dst >> 8), LDS-binned ----------
__global__ __launch_bounds__(256) void k_hist(const int* __restrict__ dst, int* __restrict__ bhist, int E, int NB){
  __shared__ int h[NBMAX];
  int t = threadIdx.x;
  for (int i = t; i < NBMAX; i += 256) h[i] = 0;
  __syncthreads();
  int t0 = blockIdx.x * 4096;
  #pragma unroll 4
  for (int k = 0; k < 16; ++k){
    int i = t0 + (k << 8) + t;
    if (i < E) atomicAdd(&h[dst[i] >> 8], 1);
  }
  __syncthreads();
  for (int b = t; b < NB; b += 256) if (h[b]) atomicAdd(&bhist[b], h[b]);
}

// ---------- 2. scan bucket sizes -> bases & cursors; off[N]=E ----------
__global__ __launch_bounds__(512) void k_bscan(const int* __restrict__ bhist, int* __restrict__ bbase,
                                               int* __restrict__ bcur, int* __restrict__ off, int NB, int N){
  __shared__ int sh[512];
  int t = threadIdx.x;
  int v = (t < NB) ? bhist[t] : 0;
  sh[t] = v; __syncthreads();
  for (int o = 1; o < 512; o <<= 1){
    int a = (t >= o) ? sh[t-o] : 0;
    __syncthreads();
    sh[t] += a;
    __syncthreads();
  }
  if (t < NB){ bbase[t] = sh[t] - v; bcur[t] = sh[t] - v; }
  if (t == 511) off[N] = sh[511];
}

// ---------- 3. partition edges into bucket-contiguous runs (LDS staged) ----------
__global__ __launch_bounds__(256) void k_part(const int* __restrict__ src, const int* __restrict__ dst,
    const float* __restrict__ w, int* __restrict__ bcur, int2* __restrict__ part, int E, int NB){
  __shared__ int2 stage[TPART];            // 64 KB
  __shared__ int hist[NBMAX];
  __shared__ int scn[NBMAX];
  __shared__ int cnt2[NBMAX];
  __shared__ int baseg[NBMAX];
  const int t = threadIdx.x;
  const int t0 = blockIdx.x * TPART;
  for (int i = t; i < NBMAX; i += 256){ hist[i] = 0; cnt2[i] = 0; }
  __syncthreads();
  // phase 1: histogram
  #pragma unroll 4
  for (int k = 0; k < 32; ++k){
    int i = t0 + (k << 8) + t;
    if (i < E) atomicAdd(&hist[dst[i] >> 8], 1);
  }
  __syncthreads();
  // phase 2: inclusive scan of hist (512-wide, 2 elems/thread)
  scn[t] = hist[t]; scn[t+256] = hist[t+256];
  __syncthreads();
  for (int o = 1; o < 512; o <<= 1){
    int a0 = (t >= o) ? scn[t-o] : 0;
    int a1 = scn[t+256-o];
    __syncthreads();
    scn[t] += a0; scn[t+256] += a1;
    __syncthreads();
  }
  // phase 3: reserve global runs
  for (int b = t; b < NB; b += 256) baseg[b] = hist[b] ? atomicAdd(&bcur[b], hist[b]) : 0;
  __syncthreads();
  // phase 4: stage records grouped by bucket
  #pragma unroll 4
  for (int k = 0; k < 32; ++k){
    int i = t0 + (k << 8) + t;
    if (i < E){
      int d = dst[i], b = d >> 8;
      int r = atomicAdd(&cnt2[b], 1);
      int pos = scn[b] - hist[b] + r;
      stage[pos] = make_int2(((d & 255) << 17) | src[i], __float_as_int(w[i]));
    }
  }
  __syncthreads();
  // phase 5: coalesced flush, one wave strides buckets
  int wv = t >> 6, ln = t & 63;
  for (int b = wv; b < NB; b += 4){
    int c = hist[b];
    if (!c) continue;
    int lo = scn[b] - c, gb = baseg[b];
    for (int s = ln; s < c; s += 64) part[gb + s] = stage[lo + s];
  }
}

// ---------- 4. exact fill per bucket: off[] + csr[] (L2-window-local) ----------
__global__ __launch_bounds__(256) void k_fill2(const int2* __restrict__ part, const int* __restrict__ bhist,
    const int* __restrict__ bbase, int* __restrict__ off, int2* __restrict__ csr, int N){
  __shared__ int deg[256], scn[256], c2[256];
  const int b = blockIdx.x, t = threadIdx.x;
  const int base = bbase[b], cnt = bhist[b];
  const int d0 = b << 8;
  const int nd = min(256, N - d0);
  deg[t] = 0; c2[t] = 0;
  __syncthreads();
  for (int s = t; s < cnt; s += 256) atomicAdd(&deg[(part[base+s].x >> 17) & 255], 1);
  __syncthreads();
  scn[t] = deg[t];
  __syncthreads();
  for (int o = 1; o < 256; o <<= 1){
    int a = (t >= o) ? scn[t-o] : 0;
    __syncthreads();
    scn[t] += a;
    __syncthreads();
  }
  if (t < nd) off[d0 + t] = base + scn[t] - deg[t];
  __syncthreads();
  for (int s = t; s < cnt; s += 256){
    int2 rec = part[base + s];
    int dl = (rec.x >> 17) & 255;
    int p = base + scn[dl] - deg[dl] + atomicAdd(&c2[dl], 1);
    csr[p] = make_int2(rec.x & 0x1FFFF, rec.y);
  }
}

// ---------- GEMM1: Y(bf16) = A @ W  (n x 128 @ 128 x 128) ----------
// 512 thr = 8 waves, tile 128x128, micro 8x4. 2 blocks/CU -> 4 waves/SIMD.
__global__ __launch_bounds__(512, 4) void k_gemm1(const float* __restrict__ A, const float* __restrict__ W,
                                                  unsigned short* __restrict__ Y, int n){
  __shared__ float As[128*129];
  const int tid = threadIdx.x;
  const int r0 = blockIdx.x * 128;
  {
    int rr = tid >> 5;                 // 0..15
    const int k4 = (tid & 31) * 4;
    #pragma unroll
    for (int p = 0; p < 8; ++p, rr += 16){
      int rg = r0 + rr; if (rg > n-1) rg = n-1;
      float4 v = *(const float4*)(A + (size_t)rg*NF + k4);
      float* d = As + rr*129 + k4;
      d[0]=v.x; d[1]=v.y; d[2]=v.z; d[3]=v.w;
    }
  }
  __syncthreads();
  const int tx = tid & 31, ty = tid >> 5;   // 32 cols-groups x 16 row-groups
  float acc[8][4] = {};
  #pragma unroll 2
  for (int k = 0; k < 128; ++k){
    float a[8];
    #pragma unroll
    for (int i = 0; i < 8; ++i) a[i] = As[(ty*8+i)*129 + k];   // 2-way broadcast: free
    float4 b = *(const float4*)(W + k*NF + tx*4);              // 512B/wave contiguous
    #pragma unroll
    for (int i = 0; i < 8; ++i){
      acc[i][0] = fmaf(a[i], b.x, acc[i][0]); acc[i][1] = fmaf(a[i], b.y, acc[i][1]);
      acc[i][2] = fmaf(a[i], b.z, acc[i][2]); acc[i][3] = fmaf(a[i], b.w, acc[i][3]);
    }
  }
  #pragma unroll
  for (int i = 0; i < 8; ++i){
    int rg = r0 + ty*8 + i;
    if (rg < n){
      uint2 p;
      p.x = (unsigned)f2bf(acc[i][0]) | ((unsigned)f2bf(acc[i][1]) << 16);
      p.y = (unsigned)f2bf(acc[i][2]) | ((unsigned)f2bf(acc[i][3]) << 16);
      *(uint2*)(Y + (size_t)rg*NF + tx*4) = p;
    }
  }
}

// ---------- GEMM2: G(bf16) = H @ W1  (n x 128 @ 128 x 64), micro 4x4 ----------
__global__ __launch_bounds__(512, 4) void k_gemm2(const float* __restrict__ A, const float* __restrict__ W,
                                                  unsigned short* __restrict__ G, int n){
  __shared__ float As[128*129];
  const int tid = threadIdx.x;
  const int r0 = blockIdx.x * 128;
  {
    int rr = tid >> 5;
    const int k4 = (tid & 31) * 4;
    #pragma unroll
    for (int p = 0; p < 8; ++p, rr += 16){
      int rg = r0 + rr; if (rg > n-1) rg = n-1;
      float4 v = *(const float4*)(A + (size_t)rg*NF + k4);
      float* d = As + rr*129 + k4;
      d[0]=v.x; d[1]=v.y; d[2]=v.z; d[3]=v.w;
    }
  }
  __syncthreads();
  const int tx = tid & 15, ty = tid >> 4;   // 16 col-groups x 32 row-groups
  float acc[4][4] = {};
  #pragma unroll 2
  for (int k = 0; k < 128; ++k){
    float a[4];
    #pragma unroll
    for (int i = 0; i < 4; ++i) a[i] = As[(ty*4+i)*129 + k];   // 4 distinct banks: free
    float4 b = *(const float4*)(W + k*NC + tx*4);
    #pragma unroll
    for (int i = 0; i < 4; ++i){
      acc[i][0] = fmaf(a[i], b.x, acc[i][0]); acc[i][1] = fmaf(a[i], b.y, acc[i][1]);
      acc[i][2] = fmaf(a[i], b.z, acc[i][2]); acc[i][3] = fmaf(a[i], b.w, acc[i][3]);
    }
  }
  #pragma unroll
  for (int i = 0; i < 4; ++i){
    int rg = r0 + ty*4 + i;
    if (rg < n){
      uint2 p;
      p.x = (unsigned)f2bf(acc[i][0]) | ((unsigned)f2bf(acc[i][1]) << 16);
      p.y = (unsigned)f2bf(acc[i][2]) | ((unsigned)f2bf(acc[i][3]) << 16);
      *(uint2*)(G + (size_t)rg*NC + tx*4) = p;
    }
  }
}

// ---------- SpMM1 + bias + ReLU: h = relu(A@y + b0); y bf16, 8-deep MLP ----------
__global__ __launch_bounds__(256) void k_spmm_relu(const unsigned short* __restrict__ y, const int2* __restrict__ csr,
    const int* __restrict__ off, const float* __restrict__ bias, float* __restrict__ h, int n){
  int wid  = (blockIdx.x * 256 + threadIdx.x) >> 6;
  int lane = threadIdx.x & 63;
  if (wid >= n) return;
  int s = off[wid], e = off[wid+1];
  float ax[8], ay[8];
  #pragma unroll
  for (int k = 0; k < 8; ++k){ ax[k] = 0.f; ay[k] = 0.f; }
  for (int j = s; j < e; j += 8){
    int2 ed[8];
    #pragma unroll
    for (int k = 0; k < 8; ++k){
      int id = j + k; if (id > e-1) id = e-1;
      ed[k] = csr[id];                               // wave-uniform -> broadcast
    }
    unsigned v[8];
    #pragma unroll
    for (int k = 0; k < 8; ++k)
      v[k] = ((const unsigned*)(y + (size_t)ed[k].x * NF))[lane];   // 256B coalesced bf16 row
    #pragma unroll
    for (int k = 0; k < 8; ++k){
      float w = (j + k < e) ? __int_as_float(ed[k].y) : 0.f;
      ax[k] = fmaf(w, bflo(v[k]), ax[k]);
      ay[k] = fmaf(w, bfhi(v[k]), ay[k]);
    }
  }
  float sx = ((ax[0]+ax[1]) + (ax[2]+ax[3])) + ((ax[4]+ax[5]) + (ax[6]+ax[7]));
  float sy = ((ay[0]+ay[1]) + (ay[2]+ay[3])) + ((ay[4]+ay[5]) + (ay[6]+ay[7]));
  float2 bb = ((const float2*)bias)[lane];
  ((float2*)(h + (size_t)wid * NF))[lane] = make_float2(fmaxf(sx+bb.x, 0.f), fmaxf(sy+bb.y, 0.f));
}

// ---------- SpMM2 + bias + log_softmax: out = ls(A@g + b1); g bf16, lane==class ----------
__global__ __launch_bounds__(256) void k_spmm_ls(const unsigned short* __restrict__ g, const int2* __restrict__ csr,
    const int* __restrict__ off, const float* __restrict__ bias, float* __restrict__ out, int n){
  int wid  = (blockIdx.x * 256 + threadIdx.x) >> 6;
  int lane = threadIdx.x & 63;
  if (wid >= n) return;
  int s = off[wid], e = off[wid+1];
  float z[8];
  #pragma unroll
  for (int k = 0; k < 8; ++k) z[k] = 0.f;
  for (int j = s; j < e; j += 8){
    int2 ed[8];
    #pragma unroll
    for (int k = 0; k < 8; ++k){
      int id = j + k; if (id > e-1) id = e-1;
      ed[k] = csr[id];
    }
    unsigned short v[8];
    #pragma unroll
    for (int k = 0; k < 8; ++k)
      v[k] = (g + (size_t)ed[k].x * NC)[lane];       // 128B coalesced bf16 row
    #pragma unroll
    for (int k = 0; k < 8; ++k){
      float w = (j + k < e) ? __int_as_float(ed[k].y) : 0.f;
      z[k] = fmaf(w, bflo((unsigned)v[k]), z[k]);
    }
  }
  float zz = ((z[0]+z[1]) + (z[2]+z[3])) + ((z[4]+z[5]) + (z[6]+z[7]));
  zz += bias[lane];
  float m = zz;
  for (int o = 32; o; o >>= 1) m = fmaxf(m, __shfl_xor(m, o));
  float sum = expf(zz - m);
  for (int o = 32; o; o >>= 1) sum += __shfl_xor(sum, o);
  out[(size_t)wid * NC + lane] = zz - m - logf(sum);
}

extern "C" void kernel_launch(void* const* d_in, const int* in_sizes, int n_in,
                              void* d_out, int out_size, void* d_ws, size_t ws_size,
                              hipStream_t stream){
  const float* x  = (const float*)d_in[0];
  const int* esrc = (const int*)d_in[1];
  const int* edst = (const int*)d_in[2];
  const float* ew = (const float*)d_in[3];
  const float* W0 = (const float*)d_in[4];
  const float* b0 = (const float*)d_in[5];
  const float* W1 = (const float*)d_in[6];
  const float* b1 = (const float*)d_in[7];
  float* out = (float*)d_out;

  const int N = in_sizes[0] / NF;
  const int E = in_sizes[1];
  const int NB = (N + 255) >> 8;            // 391 buckets of 256 dsts

  char* ws = (char*)d_ws;
  size_t o = 0;
  int*  bhist = (int*) (ws + o); o = alignup(o + NBMAX*4);
  int*  bbase = (int*) (ws + o); o = alignup(o + NBMAX*4);
  int*  bcur  = (int*) (ws + o); o = alignup(o + NBMAX*4);
  int*  off   = (int*) (ws + o); o = alignup(o + (size_t)(N+1)*4);
  int2* part  = (int2*)(ws + o); o = alignup(o + (size_t)E*8);
  int2* csr   = (int2*)(ws + o); o = alignup(o + (size_t)E*8);
  unsigned short* y = (unsigned short*)(ws + o); o = alignup(o + (size_t)N*NF*2);  // bf16; reused as g
  float* h    = (float*)(ws + o); o = alignup(o + (size_t)N*NF*4);
  unsigned short* g = y;  // y dead after k_spmm_relu

  hipMemsetAsync(bhist, 0, NBMAX*4, stream);

  const int hb = (E + 4095)/4096;
  const int pb = (E + TPART-1)/TPART;

  k_hist <<<hb, 256, 0, stream>>>(edst, bhist, E, NB);
  k_bscan<<<1, 512, 0, stream>>>(bhist, bbase, bcur, off, NB, N);
  k_part <<<pb, 256, 0, stream>>>(esrc, edst, ew, bcur, part, E, NB);
  k_fill2<<<NB, 256, 0, stream>>>(part, bhist, bbase, off, csr, N);

  const int gb = (N + 127)/128;
  const int sb = (N + 3)/4;

  k_gemm1<<<gb, 512, 0, stream>>>(x, W0, y, N);               // y = bf16(x @ W0)
  k_spmm_relu<<<sb, 256, 0, stream>>>(y, csr, off, b0, h, N); // h = relu(A y + b0)
  k_gemm2<<<gb, 512, 0, stream>>>(h, W1, g, N);               // g = bf16(h @ W1)
  k_spmm_ls<<<sb, 256, 0, stream>>>(g, csr, off, b1, out, N); // out = log_softmax(A g + b1)
}

// Round 7
// 316.013 us; speedup vs baseline: 2.6871x; 1.1019x over previous
//
#include <hip/hip_runtime.h>

#define NF 128
#define NC 64
#define NBMAX 512          // max dst-buckets (N/256 = 391 for N=100000)
#define TPART 8192         // edges per k_part block

static inline size_t alignup(size_t x){ return (x + 255) & ~(size_t)255; }

__device__ __forceinline__ unsigned short f2bf(float f){
  unsigned u = __float_as_uint(f);
  u += 0x7fffu + ((u >> 16) & 1u);       // round-to-nearest-even
  return (unsigned short)(u >> 16);
}
__device__ __forceinline__ float bflo(unsigned u){ return __uint_as_float(u << 16); }
__device__ __forceinline__ float bfhi(unsigned u){ return __uint_as_float(u & 0xffff0000u); }

// ---------- 1. bucket histogram (bucket = dst >> 8), LDS-binned ----------
__global__ __launch_bounds__(256) void k_hist(const int* __restrict__ dst, int* __restrict__ bhist, int E, int NB){
  __shared__ int h[NBMAX];
  int t = threadIdx.x;
  for (int i = t; i < NBMAX; i += 256) h[i] = 0;
  __syncthreads();
  int t0 = blockIdx.x * 4096;
  #pragma unroll 4
  for (int k = 0; k < 16; ++k){
    int i = t0 + (k << 8) + t;
    if (i < E) atomicAdd(&h[dst[i] >> 8], 1);
  }
  __syncthreads();
  for (int b = t; b < NB; b += 256) if (h[b]) atomicAdd(&bhist[b], h[b]);
}

// ---------- 2. scan bucket sizes -> bases & cursors; off[N]=E ----------
__global__ __launch_bounds__(512) void k_bscan(const int* __restrict__ bhist, int* __restrict__ bbase,
                                               int* __restrict__ bcur, int* __restrict__ off, int NB, int N){
  __shared__ int sh[512];
  int t = threadIdx.x;
  int v = (t < NB) ? bhist[t] : 0;
  sh[t] = v; __syncthreads();
  for (int o = 1; o < 512; o <<= 1){
    int a = (t >= o) ? sh[t-o] : 0;
    __syncthreads();
    sh[t] += a;
    __syncthreads();
  }
  if (t < NB){ bbase[t] = sh[t] - v; bcur[t] = sh[t] - v; }
  if (t == 511) off[N] = sh[511];
}

// ---------- 3. partition edges into bucket-contiguous runs (LDS staged) ----------
__global__ __launch_bounds__(256) void k_part(const int* __restrict__ src, const int* __restrict__ dst,
    const float* __restrict__ w, int* __restrict__ bcur, int2* __restrict__ part, int E, int NB){
  __shared__ int2 stage[TPART];            // 64 KB
  __shared__ int hist[NBMAX];
  __shared__ int scn[NBMAX];
  __shared__ int cnt2[NBMAX];
  __shared__ int baseg[NBMAX];
  const int t = threadIdx.x;
  const int t0 = blockIdx.x * TPART;
  for (int i = t; i < NBMAX; i += 256){ hist[i] = 0; cnt2[i] = 0; }
  __syncthreads();
  // phase 1: histogram
  #pragma unroll 4
  for (int k = 0; k < 32; ++k){
    int i = t0 + (k << 8) + t;
    if (i < E) atomicAdd(&hist[dst[i] >> 8], 1);
  }
  __syncthreads();
  // phase 2: inclusive scan of hist (512-wide, 2 elems/thread)
  scn[t] = hist[t]; scn[t+256] = hist[t+256];
  __syncthreads();
  for (int o = 1; o < 512; o <<= 1){
    int a0 = (t >= o) ? scn[t-o] : 0;
    int a1 = scn[t+256-o];
    __syncthreads();
    scn[t] += a0; scn[t+256] += a1;
    __syncthreads();
  }
  // phase 3: reserve global runs
  for (int b = t; b < NB; b += 256) baseg[b] = hist[b] ? atomicAdd(&bcur[b], hist[b]) : 0;
  __syncthreads();
  // phase 4: stage records grouped by bucket
  #pragma unroll 4
  for (int k = 0; k < 32; ++k){
    int i = t0 + (k << 8) + t;
    if (i < E){
      int d = dst[i], b = d >> 8;
      int r = atomicAdd(&cnt2[b], 1);
      int pos = scn[b] - hist[b] + r;
      stage[pos] = make_int2(((d & 255) << 17) | src[i], __float_as_int(w[i]));
    }
  }
  __syncthreads();
  // phase 5: coalesced flush, one wave strides buckets
  int wv = t >> 6, ln = t & 63;
  for (int b = wv; b < NB; b += 4){
    int c = hist[b];
    if (!c) continue;
    int lo = scn[b] - c, gb = baseg[b];
    for (int s = ln; s < c; s += 64) part[gb + s] = stage[lo + s];
  }
}

// ---------- 4. exact fill per bucket: off[] + csr[] (L2-window-local) ----------
__global__ __launch_bounds__(256) void k_fill2(const int2* __restrict__ part, const int* __restrict__ bhist,
    const int* __restrict__ bbase, int* __restrict__ off, int2* __restrict__ csr, int N){
  __shared__ int deg[256], scn[256], c2[256];
  const int b = blockIdx.x, t = threadIdx.x;
  const int base = bbase[b], cnt = bhist[b];
  const int d0 = b << 8;
  const int nd = min(256, N - d0);
  deg[t] = 0; c2[t] = 0;
  __syncthreads();
  for (int s = t; s < cnt; s += 256) atomicAdd(&deg[(part[base+s].x >> 17) & 255], 1);
  __syncthreads();
  scn[t] = deg[t];
  __syncthreads();
  for (int o = 1; o < 256; o <<= 1){
    int a = (t >= o) ? scn[t-o] : 0;
    __syncthreads();
    scn[t] += a;
    __syncthreads();
  }
  if (t < nd) off[d0 + t] = base + scn[t] - deg[t];
  __syncthreads();
  for (int s = t; s < cnt; s += 256){
    int2 rec = part[base + s];
    int dl = (rec.x >> 17) & 255;
    int p = base + scn[dl] - deg[dl] + atomicAdd(&c2[dl], 1);
    csr[p] = make_int2(rec.x & 0x1FFFF, rec.y);
  }
}

// ---------- GEMM1: Y(bf16) = A @ W  (n x 128 @ 128 x 128) ----------
// 512 thr = 8 waves, tile 128x128, micro 8x4. 2 blocks/CU -> 4 waves/SIMD.
__global__ __launch_bounds__(512, 4) void k_gemm1(const float* __restrict__ A, const float* __restrict__ W,
                                                  unsigned short* __restrict__ Y, int n){
  __shared__ float As[128*129];
  const int tid = threadIdx.x;
  const int r0 = blockIdx.x * 128;
  {
    int rr = tid >> 5;                 // 0..15
    const int k4 = (tid & 31) * 4;
    #pragma unroll
    for (int p = 0; p < 8; ++p, rr += 16){
      int rg = r0 + rr; if (rg > n-1) rg = n-1;
      float4 v = *(const float4*)(A + (size_t)rg*NF + k4);
      float* d = As + rr*129 + k4;
      d[0]=v.x; d[1]=v.y; d[2]=v.z; d[3]=v.w;
    }
  }
  __syncthreads();
  const int tx = tid & 31, ty = tid >> 5;   // 32 cols-groups x 16 row-groups
  float acc[8][4] = {};
  #pragma unroll 2
  for (int k = 0; k < 128; ++k){
    float a[8];
    #pragma unroll
    for (int i = 0; i < 8; ++i) a[i] = As[(ty*8+i)*129 + k];   // 2-way broadcast: free
    float4 b = *(const float4*)(W + k*NF + tx*4);              // 512B/wave contiguous
    #pragma unroll
    for (int i = 0; i < 8; ++i){
      acc[i][0] = fmaf(a[i], b.x, acc[i][0]); acc[i][1] = fmaf(a[i], b.y, acc[i][1]);
      acc[i][2] = fmaf(a[i], b.z, acc[i][2]); acc[i][3] = fmaf(a[i], b.w, acc[i][3]);
    }
  }
  #pragma unroll
  for (int i = 0; i < 8; ++i){
    int rg = r0 + ty*8 + i;
    if (rg < n){
      uint2 p;
      p.x = (unsigned)f2bf(acc[i][0]) | ((unsigned)f2bf(acc[i][1]) << 16);
      p.y = (unsigned)f2bf(acc[i][2]) | ((unsigned)f2bf(acc[i][3]) << 16);
      *(uint2*)(Y + (size_t)rg*NF + tx*4) = p;
    }
  }
}

// ---------- GEMM2: G(bf16) = H @ W1  (n x 128 @ 128 x 64), micro 4x4 ----------
__global__ __launch_bounds__(512, 4) void k_gemm2(const float* __restrict__ A, const float* __restrict__ W,
                                                  unsigned short* __restrict__ G, int n){
  __shared__ float As[128*129];
  const int tid = threadIdx.x;
  const int r0 = blockIdx.x * 128;
  {
    int rr = tid >> 5;
    const int k4 = (tid & 31) * 4;
    #pragma unroll
    for (int p = 0; p < 8; ++p, rr += 16){
      int rg = r0 + rr; if (rg > n-1) rg = n-1;
      float4 v = *(const float4*)(A + (size_t)rg*NF + k4);
      float* d = As + rr*129 + k4;
      d[0]=v.x; d[1]=v.y; d[2]=v.z; d[3]=v.w;
    }
  }
  __syncthreads();
  const int tx = tid & 15, ty = tid >> 4;   // 16 col-groups x 32 row-groups
  float acc[4][4] = {};
  #pragma unroll 2
  for (int k = 0; k < 128; ++k){
    float a[4];
    #pragma unroll
    for (int i = 0; i < 4; ++i) a[i] = As[(ty*4+i)*129 + k];   // 4 distinct banks: free
    float4 b = *(const float4*)(W + k*NC + tx*4);
    #pragma unroll
    for (int i = 0; i < 4; ++i){
      acc[i][0] = fmaf(a[i], b.x, acc[i][0]); acc[i][1] = fmaf(a[i], b.y, acc[i][1]);
      acc[i][2] = fmaf(a[i], b.z, acc[i][2]); acc[i][3] = fmaf(a[i], b.w, acc[i][3]);
    }
  }
  #pragma unroll
  for (int i = 0; i < 4; ++i){
    int rg = r0 + ty*4 + i;
    if (rg < n){
      uint2 p;
      p.x = (unsigned)f2bf(acc[i][0]) | ((unsigned)f2bf(acc[i][1]) << 16);
      p.y = (unsigned)f2bf(acc[i][2]) | ((unsigned)f2bf(acc[i][3]) << 16);
      *(uint2*)(G + (size_t)rg*NC + tx*4) = p;
    }
  }
}

// ---------- SpMM1 + bias + ReLU: h = relu(A@y + b0); y bf16, 8-deep MLP ----------
// Scalar-pipe edge walk: row bounds, edge records, weights and row bases are
// wave-uniform -> readfirstlane to SGPRs; gathers use saddr form (zero VALU addr math).
__global__ __launch_bounds__(256) void k_spmm_relu(const unsigned short* __restrict__ y, const int2* __restrict__ csr,
    const int* __restrict__ off, const float* __restrict__ bias, float* __restrict__ h, int n){
  int wid  = (blockIdx.x * 256 + threadIdx.x) >> 6;
  int lane = threadIdx.x & 63;
  if (wid >= n) return;
  const int s = __builtin_amdgcn_readfirstlane(off[wid]);
  const int e = __builtin_amdgcn_readfirstlane(off[wid+1]);
  float ax[8], ay[8];
  #pragma unroll
  for (int k = 0; k < 8; ++k){ ax[k] = 0.f; ay[k] = 0.f; }
  for (int j = s; j < e; j += 8){
    int  sk[8];  float wk[8];
    #pragma unroll
    for (int k = 0; k < 8; ++k){
      int id = j + k; if (id > e-1) id = e-1;           // scalar clamp
      int2 ed = csr[id];                                // uniform address
      sk[k] = __builtin_amdgcn_readfirstlane(ed.x);     // SGPR row index
      int wbits = __builtin_amdgcn_readfirstlane(ed.y);
      wk[k] = (j + k < e) ? __int_as_float(wbits) : 0.f; // scalar select
    }
    unsigned v[8];
    #pragma unroll
    for (int k = 0; k < 8; ++k)
      v[k] = ((const unsigned*)(y + (size_t)sk[k] * NF))[lane];  // saddr gather, 256B/row
    #pragma unroll
    for (int k = 0; k < 8; ++k){
      ax[k] = fmaf(wk[k], bflo(v[k]), ax[k]);
      ay[k] = fmaf(wk[k], bfhi(v[k]), ay[k]);
    }
  }
  float sx = ((ax[0]+ax[1]) + (ax[2]+ax[3])) + ((ax[4]+ax[5]) + (ax[6]+ax[7]));
  float sy = ((ay[0]+ay[1]) + (ay[2]+ay[3])) + ((ay[4]+ay[5]) + (ay[6]+ay[7]));
  float2 bb = ((const float2*)bias)[lane];
  ((float2*)(h + (size_t)wid * NF))[lane] = make_float2(fmaxf(sx+bb.x, 0.f), fmaxf(sy+bb.y, 0.f));
}

// ---------- SpMM2 + bias + log_softmax: out = ls(A@g + b1); g bf16, lane==class ----------
__global__ __launch_bounds__(256) void k_spmm_ls(const unsigned short* __restrict__ g, const int2* __restrict__ csr,
    const int* __restrict__ off, const float* __restrict__ bias, float* __restrict__ out, int n){
  int wid  = (blockIdx.x * 256 + threadIdx.x) >> 6;
  int lane = threadIdx.x & 63;
  if (wid >= n) return;
  const int s = __builtin_amdgcn_readfirstlane(off[wid]);
  const int e = __builtin_amdgcn_readfirstlane(off[wid+1]);
  float z[8];
  #pragma unroll
  for (int k = 0; k < 8; ++k) z[k] = 0.f;
  for (int j = s; j < e; j += 8){
    int  sk[8];  float wk[8];
    #pragma unroll
    for (int k = 0; k < 8; ++k){
      int id = j + k; if (id > e-1) id = e-1;
      int2 ed = csr[id];
      sk[k] = __builtin_amdgcn_readfirstlane(ed.x);
      int wbits = __builtin_amdgcn_readfirstlane(ed.y);
      wk[k] = (j + k < e) ? __int_as_float(wbits) : 0.f;
    }
    unsigned short v[8];
    #pragma unroll
    for (int k = 0; k < 8; ++k)
      v[k] = (g + (size_t)sk[k] * NC)[lane];            // saddr gather, 128B/row
    #pragma unroll
    for (int k = 0; k < 8; ++k)
      z[k] = fmaf(wk[k], bflo((unsigned)v[k]), z[k]);
  }
  float zz = ((z[0]+z[1]) + (z[2]+z[3])) + ((z[4]+z[5]) + (z[6]+z[7]));
  zz += bias[lane];
  float m = zz;
  for (int o = 32; o; o >>= 1) m = fmaxf(m, __shfl_xor(m, o));
  float sum = expf(zz - m);
  for (int o = 32; o; o >>= 1) sum += __shfl_xor(sum, o);
  out[(size_t)wid * NC + lane] = zz - m - logf(sum);
}

extern "C" void kernel_launch(void* const* d_in, const int* in_sizes, int n_in,
                              void* d_out, int out_size, void* d_ws, size_t ws_size,
                              hipStream_t stream){
  const float* x  = (const float*)d_in[0];
  const int* esrc = (const int*)d_in[1];
  const int* edst = (const int*)d_in[2];
  const float* ew = (const float*)d_in[3];
  const float* W0 = (const float*)d_in[4];
  const float* b0 = (const float*)d_in[5];
  const float* W1 = (const float*)d_in[6];
  const float* b1 = (const float*)d_in[7];
  float* out = (float*)d_out;

  const int N = in_sizes[0] / NF;
  const int E = in_sizes[1];
  const int NB = (N + 255) >> 8;            // 391 buckets of 256 dsts

  char* ws = (char*)d_ws;
  size_t o = 0;
  int*  bhist = (int*) (ws + o); o = alignup(o + NBMAX*4);
  int*  bbase = (int*) (ws + o); o = alignup(o + NBMAX*4);
  int*  bcur  = (int*) (ws + o); o = alignup(o + NBMAX*4);
  int*  off   = (int*) (ws + o); o = alignup(o + (size_t)(N+1)*4);
  int2* part  = (int2*)(ws + o); o = alignup(o + (size_t)E*8);
  int2* csr   = (int2*)(ws + o); o = alignup(o + (size_t)E*8);
  unsigned short* y = (unsigned short*)(ws + o); o = alignup(o + (size_t)N*NF*2);  // bf16; reused as g
  float* h    = (float*)(ws + o); o = alignup(o + (size_t)N*NF*4);
  unsigned short* g = y;  // y dead after k_spmm_relu

  hipMemsetAsync(bhist, 0, NBMAX*4, stream);

  const int hb = (E + 4095)/4096;
  const int pb = (E + TPART-1)/TPART;

  k_hist <<<hb, 256, 0, stream>>>(edst, bhist, E, NB);
  k_bscan<<<1, 512, 0, stream>>>(bhist, bbase, bcur, off, NB, N);
  k_part <<<pb, 256, 0, stream>>>(esrc, edst, ew, bcur, part, E, NB);
  k_fill2<<<NB, 256, 0, stream>>>(part, bhist, bbase, off, csr, N);

  const int gb = (N + 127)/128;
  const int sb = (N + 3)/4;

  k_gemm1<<<gb, 512, 0, stream>>>(x, W0, y, N);               // y = bf16(x @ W0)
  k_spmm_relu<<<sb, 256, 0, stream>>>(y, csr, off, b0, h, N); // h = relu(A y + b0)
  k_gemm2<<<gb, 512, 0, stream>>>(h, W1, g, N);               // g = bf16(h @ W1)
  k_spmm_ls<<<sb, 256, 0, stream>>>(g, csr, off, b1, out, N); // out = log_softmax(A g + b1)
}